// Round 8
// baseline (251.771 us; speedup 1.0000x reference)
//
#include <hip/hip_runtime.h>
#include <math.h>

#define B_    128
#define C_    768
#define O_    192
#define HW_   289
#define N_IN  (128*768*289)
#define N_OUT (128*192*289)
#define QN_   127.0f

// quant_pool geometry: 16 planes/block, padded LDS [19][20] per plane
#define PPG    16
#define QP_E   (PPG*289)          // 4624 elements
#define QP_LDS (PPG*380)          // 6080 f32 slots
#define NTASKS (PPG*17*5)         // 1360 (plane, row, 4-col chunk)
#define NG     6144               // 98304/16

typedef __attribute__((ext_vector_type(8))) short bf16x8;
typedef __attribute__((ext_vector_type(4))) float f32x4;

// XOR swizzle within a 64B row: flip 16B-chunk bits (4..5) by row bits (6..7). Involution.
#define SWZ(b) ((b) ^ ((((b) >> 6) & 3) << 4))

// ws layout:
//  0     : cnt[0]=absmax(x) bits, cnt[1]=max|pooled| int, cnt[2]=absmax(out) bits
//  1024  : f32 b_int[192]
//  2048  : f32 scale_o[192]
//  3072  : u16 lut[2305]
//  8192  : u16 w_q bf16 image, [kt][o][cc] linear, 24*6144 u16
//  1MiB  : i16 pooledT[128][289][768]  (transposed: hw-major)

__global__ void k_absmax_x(const float4* __restrict__ x4, int n4, unsigned* cnt) {
    float m = 0.f;
    for (int i = blockIdx.x * blockDim.x + threadIdx.x; i < n4;
         i += gridDim.x * blockDim.x) {
        float4 v = x4[i];
        m = fmaxf(m, fmaxf(fmaxf(fabsf(v.x), fabsf(v.y)),
                           fmaxf(fabsf(v.z), fabsf(v.w))));
    }
#pragma unroll
    for (int off = 32; off; off >>= 1) m = fmaxf(m, __shfl_down(m, off));
    __shared__ float sm[4];
    int lane = threadIdx.x & 63, wv = threadIdx.x >> 6;
    if (lane == 0) sm[wv] = m;
    __syncthreads();
    if (threadIdx.x == 0) {
        float bm = fmaxf(fmaxf(sm[0], sm[1]), fmaxf(sm[2], sm[3]));
        atomicMax(cnt + 0, __float_as_uint(bm));
    }
}

// Quantize + 3x3 zero-pad pooling via padded LDS planes, float4 taps.
// Task = (plane, row, 4-col chunk): 6 ds_read_b128 -> 4 outputs.
__launch_bounds__(512) __global__
void k_quant_pool(const float* __restrict__ x, short* __restrict__ pooledT,
                  unsigned* cnt) {
    __shared__ __align__(16) float fq[QP_LDS + 8];
    __shared__ int smax[8];
    const int tid = threadIdx.x;
    const int g = blockIdx.x;
    const float s0 = fmaxf(__uint_as_float(cnt[0]) / QN_, 1e-8f);

    for (int i = tid; i < QP_LDS + 8; i += 512) fq[i] = 0.f;
    __syncthreads();

    // quant: float4 loads, per-element padded scatter (r+1, c+1)
    const float4* xg4 = (const float4*)(x + (size_t)g * QP_E);
    for (int t = tid; t < QP_E / 4; t += 512) {
        float4 v = xg4[t];
        int e = t * 4;
#pragma unroll
        for (int j = 0; j < 4; ++j) {
            float xv = (j == 0) ? v.x : (j == 1) ? v.y : (j == 2) ? v.z : v.w;
            float q = fminf(fmaxf(rintf(xv / s0), -128.f), 127.f);
            int ej = e + j;
            int p = (ej * 29027) >> 23;          // ej/289
            int i2 = ej - p * 289;
            int r = (i2 * 3856) >> 16;           // i2/17
            int c = i2 - r * 17;
            fq[p * 380 + (r + 1) * 20 + (c + 1)] = q;
        }
    }
    __syncthreads();

    // pool: task -> (p, r, t5); base padded (r, c=4*t5); 6 float4 taps.
    const int b = g / 48;
    const int cb = (g - b * 48) * 16;
    int tmax = 0;
    for (int task = tid; task < NTASKS; task += 512) {
        int pr = task / 5;                 // 0..271
        int t5 = task - pr * 5;            // 0..4
        int p = (pr * 3856) >> 16;         // pr/17
        int r = pr - p * 17;
        const float* base = fq + p * 380 + r * 20 + t5 * 4;
        float4 a0 = *(const float4*)(base);
        float4 a1 = *(const float4*)(base + 4);
        float4 b0 = *(const float4*)(base + 20);
        float4 b1 = *(const float4*)(base + 24);
        float4 d0 = *(const float4*)(base + 40);
        float4 d1 = *(const float4*)(base + 44);
        float s0c = a0.x + b0.x + d0.x;
        float s1c = a0.y + b0.y + d0.y;
        float s2c = a0.z + b0.z + d0.z;
        float s3c = a0.w + b0.w + d0.w;
        float s4c = a1.x + b1.x + d1.x;
        float s5c = a1.y + b1.y + d1.y;
        int o0 = (int)(s0c + s1c + s2c);
        int o1 = (int)(s1c + s2c + s3c);
        int o2 = (int)(s2c + s3c + s4c);
        int o3 = (int)(s3c + s4c + s5c);
        short* outb = pooledT + (size_t)b * (HW_ * C_) + cb + p;
        int c0 = t5 * 4;
        int i0 = r * 17 + c0;
        outb[(size_t)i0 * C_] = (short)o0;
        int a = o0 < 0 ? -o0 : o0; tmax = a > tmax ? a : tmax;
        if (c0 + 1 < 17) {
            outb[(size_t)(i0 + 1) * C_] = (short)o1;
            a = o1 < 0 ? -o1 : o1; tmax = a > tmax ? a : tmax;
            outb[(size_t)(i0 + 2) * C_] = (short)o2;
            a = o2 < 0 ? -o2 : o2; tmax = a > tmax ? a : tmax;
            outb[(size_t)(i0 + 3) * C_] = (short)o3;
            a = o3 < 0 ? -o3 : o3; tmax = a > tmax ? a : tmax;
        }
    }

#pragma unroll
    for (int off = 32; off; off >>= 1) {
        int o = __shfl_down(tmax, off);
        tmax = o > tmax ? o : tmax;
    }
    if ((tid & 63) == 0) smax[tid >> 6] = tmax;
    __syncthreads();
    if (tid == 0) {
        int bm = smax[0];
#pragma unroll
        for (int i = 1; i < 8; ++i) bm = smax[i] > bm ? smax[i] : bm;
        atomicMax((int*)(cnt + 1), bm);
    }
}

// BN-fold + per-channel weight quant -> bf16 image; block 192 computes the xi LUT.
__global__ void k_weights(const float* __restrict__ conv_w,
                          const float* __restrict__ g,
                          const float* __restrict__ beta,
                          const float* __restrict__ mu,
                          const float* __restrict__ var,
                          const unsigned* __restrict__ cnt,
                          unsigned short* __restrict__ w_q,
                          float* __restrict__ b_int, float* __restrict__ scale_o,
                          unsigned short* __restrict__ lut) {
    if (blockIdx.x == O_) {
        const float s0 = fmaxf(__uint_as_float(cnt[0]) / QN_, 1e-8f);
        const float maxx2 = ((float)((const int*)cnt)[1] / 9.0f) * s0;
        const float s1 = fmaxf(maxx2 / QN_, 1e-8f);
        for (int i = threadIdx.x; i < 2305; i += 256) {
            float p = (float)(i - 1152);
            float t = (p / 9.0f) * s0;
            float v = rintf(t / s1);
            v = fminf(fmaxf(v, -128.f), 127.f);
            lut[i] = (unsigned short)(__float_as_uint(v) >> 16);
        }
        return;
    }
    const int o = blockIdx.x;
    const float stdv = sqrtf(var[o] + 1e-5f);
    const float r = g[o] / stdv;
    const float* wo = conv_w + o * C_;
    float m = 0.f;
    for (int c = threadIdx.x; c < C_; c += 256) m = fmaxf(m, fabsf(wo[c] * r));
#pragma unroll
    for (int off = 32; off; off >>= 1) m = fmaxf(m, __shfl_down(m, off));
    __shared__ float sm[4];
    __shared__ float swsf;
    int lane = threadIdx.x & 63, wv = threadIdx.x >> 6;
    if (lane == 0) sm[wv] = m;
    __syncthreads();
    if (threadIdx.x == 0) {
        float bm = fmaxf(fmaxf(sm[0], sm[1]), fmaxf(sm[2], sm[3]));
        swsf = fmaxf(bm / QN_, 1e-8f);
    }
    __syncthreads();
    const float wsf = swsf;
    for (int c = threadIdx.x; c < C_; c += 256) {
        float wi = rintf(wo[c] * r / wsf);
        wi = fminf(fmaxf(wi, -128.f), 127.f);
        w_q[(c >> 5) * 6144 + o * 32 + (c & 31)] =
            (unsigned short)(__float_as_uint(wi) >> 16);
    }
    if (threadIdx.x == 0) {
        float s0 = fmaxf(__uint_as_float(cnt[0]) / QN_, 1e-8f);
        float maxx2 = ((float)((const int*)cnt)[1] / 9.0f) * s0;
        float s1 = fmaxf(maxx2 / QN_, 1e-8f);
        float bf = beta[o] - g[o] * mu[o] / stdv;
        b_int[o] = rintf(bf / (wsf * s1));
        scale_o[o] = wsf * s1;
    }
}

// MFMA GEMM: 512 blocks (4 hw-quarters x 128 b), 256 threads (4 waves of 48o x 80hw),
// double-buffered LDS, distance-2 X register prefetch.
__launch_bounds__(256) __global__
void k_gemm(const short* __restrict__ pooledT,
            const unsigned short* __restrict__ w_q,
            const unsigned short* __restrict__ lut_g,
            const float* __restrict__ b_int, const float* __restrict__ scale_o,
            unsigned* cnt, float* __restrict__ out) {
    __shared__ char sW[2][12288];       // [192][32] bf16, XOR-swizzled
    __shared__ char sX[2][5120];        // [80][32] bf16 (hw-major), XOR-swizzled
    __shared__ unsigned short s_lut[2305];
    __shared__ float red[4];
    const int tid = threadIdx.x;
    const int b = blockIdx.z;
    const int hw0 = blockIdx.x * 80;
    const int L = tid & 63;
    const int wv = tid >> 6;
    const int wo = wv * 48;
    const short* pb = pooledT + (size_t)b * (HW_ * C_);

    for (int i = tid; i < 2305; i += 256) s_lut[i] = lut_g[i];

    // X staging: 320 uint4 items; item0 = tid (all), item1 = 256+tid (tid<64)
    const int cg0 = tid / 80, hwr0 = tid - cg0 * 80;
    const int hwr1 = tid + 16;           // item1: cg=3, hwr = 16+tid
    const bool act1 = tid < 64;
    const int hwg0 = hw0 + hwr0, hwg1 = hw0 + hwr1;

    uint4 xrA0, xrA1, xrB0, xrB1;

    auto stageW = [&](int kt, int buf) {
#pragma unroll
        for (int j = 0; j < 3; ++j) {
            int ldsoff = (wv * 3 + j) * 1024;
            const char* src = (const char*)w_q + kt * 12288 + SWZ(ldsoff + L * 16);
            __builtin_amdgcn_global_load_lds(
                (const __attribute__((address_space(1))) unsigned int*)src,
                (__attribute__((address_space(3))) unsigned int*)(&sW[buf][0] + ldsoff),
                16, 0, 0);
        }
    };
    auto loadX = [&](int kt, uint4& r0, uint4& r1) {
        uint4 z; z.x = z.y = z.z = z.w = 0u;
        r0 = (hwg0 < HW_)
            ? *(const uint4*)(pb + (size_t)hwg0 * C_ + kt * 32 + cg0 * 8) : z;
        if (act1)
            r1 = (hwg1 < HW_)
                ? *(const uint4*)(pb + (size_t)hwg1 * C_ + kt * 32 + 24) : z;
    };
    auto writeX = [&](int buf, const uint4& r0, const uint4& r1) {
        uint4 q;
        q.x = (unsigned)s_lut[1152 + (short)(r0.x)] |
              ((unsigned)s_lut[1152 + (short)(r0.x >> 16)] << 16);
        q.y = (unsigned)s_lut[1152 + (short)(r0.y)] |
              ((unsigned)s_lut[1152 + (short)(r0.y >> 16)] << 16);
        q.z = (unsigned)s_lut[1152 + (short)(r0.z)] |
              ((unsigned)s_lut[1152 + (short)(r0.z >> 16)] << 16);
        q.w = (unsigned)s_lut[1152 + (short)(r0.w)] |
              ((unsigned)s_lut[1152 + (short)(r0.w >> 16)] << 16);
        *(uint4*)(&sX[buf][0] + SWZ(hwr0 * 64 + cg0 * 16)) = q;
        if (act1) {
            uint4 p2;
            p2.x = (unsigned)s_lut[1152 + (short)(r1.x)] |
                   ((unsigned)s_lut[1152 + (short)(r1.x >> 16)] << 16);
            p2.y = (unsigned)s_lut[1152 + (short)(r1.y)] |
                   ((unsigned)s_lut[1152 + (short)(r1.y >> 16)] << 16);
            p2.z = (unsigned)s_lut[1152 + (short)(r1.z)] |
                   ((unsigned)s_lut[1152 + (short)(r1.z >> 16)] << 16);
            p2.w = (unsigned)s_lut[1152 + (short)(r1.w)] |
                   ((unsigned)s_lut[1152 + (short)(r1.w >> 16)] << 16);
            *(uint4*)(&sX[buf][0] + SWZ(hwr1 * 64 + 3 * 16)) = p2;
        }
    };

    f32x4 acc[3][5] = {};

    loadX(0, xrA0, xrA1);
    loadX(1, xrB0, xrB1);
    stageW(0, 0);
    __syncthreads();              // lut + W(0) ready
    writeX(0, xrA0, xrA1);
    __syncthreads();              // buf0 ready

#pragma unroll
    for (int kt = 0; kt < 24; ++kt) {
        const int cur = kt & 1, nxt = cur ^ 1;
        if (kt < 23) stageW(kt + 1, nxt);
        if (kt < 22) {
            if ((kt & 1) == 0) loadX(kt + 2, xrA0, xrA1);
            else               loadX(kt + 2, xrB0, xrB1);
        }
        bf16x8 af[3], bfr[5];
#pragma unroll
        for (int m = 0; m < 3; ++m)
            af[m] = *(const bf16x8*)(&sW[cur][0] +
                SWZ((wo + m * 16 + (L & 15)) * 64 + (L >> 4) * 16));
#pragma unroll
        for (int n = 0; n < 5; ++n)
            bfr[n] = *(const bf16x8*)(&sX[cur][0] +
                SWZ((n * 16 + (L & 15)) * 64 + (L >> 4) * 16));
#pragma unroll
        for (int m = 0; m < 3; ++m)
#pragma unroll
            for (int n = 0; n < 5; ++n)
                acc[m][n] = __builtin_amdgcn_mfma_f32_16x16x32_bf16(
                    af[m], bfr[n], acc[m][n], 0, 0, 0);
        if (kt < 23) {
            if ((kt & 1) == 0) writeX(nxt, xrB0, xrB1);
            else               writeX(nxt, xrA0, xrA1);
        }
        __syncthreads();
    }

    float lmax = 0.f;
#pragma unroll
    for (int m = 0; m < 3; ++m) {
        int ob = wo + m * 16 + (L >> 4) * 4;
        float bi0 = b_int[ob + 0], bi1 = b_int[ob + 1];
        float bi2 = b_int[ob + 2], bi3 = b_int[ob + 3];
        float sc0 = scale_o[ob + 0], sc1 = scale_o[ob + 1];
        float sc2 = scale_o[ob + 2], sc3 = scale_o[ob + 3];
#pragma unroll
        for (int n = 0; n < 5; ++n) {
            int hw = hw0 + n * 16 + (L & 15);
            if (hw < HW_) {
                size_t base = ((size_t)b * O_ + ob) * HW_ + hw;
                float v0 = fmaxf((acc[m][n][0] + bi0) * sc0, 0.f);
                float v1 = fmaxf((acc[m][n][1] + bi1) * sc1, 0.f);
                float v2 = fmaxf((acc[m][n][2] + bi2) * sc2, 0.f);
                float v3 = fmaxf((acc[m][n][3] + bi3) * sc3, 0.f);
                out[base + 0 * HW_] = v0;
                out[base + 1 * HW_] = v1;
                out[base + 2 * HW_] = v2;
                out[base + 3 * HW_] = v3;
                lmax = fmaxf(fmaxf(fmaxf(v0, v1), fmaxf(v2, v3)), lmax);
            }
        }
    }
#pragma unroll
    for (int off = 32; off; off >>= 1) lmax = fmaxf(lmax, __shfl_down(lmax, off));
    if (L == 0) red[wv] = lmax;
    __syncthreads();
    if (tid == 0) {
        float bm = fmaxf(fmaxf(red[0], red[1]), fmaxf(red[2], red[3]));
        atomicMax(cnt + 2, __float_as_uint(bm));
    }
}

__global__ void k_quant_out(float* __restrict__ out, const unsigned* __restrict__ cnt) {
    const float s2 = fmaxf(__uint_as_float(cnt[2]) / QN_, 1e-8f);
    float4* o4 = (float4*)out;
    const int n4 = N_OUT / 4;
    for (int i = blockIdx.x * blockDim.x + threadIdx.x; i < n4;
         i += gridDim.x * blockDim.x) {
        float4 v = o4[i];
        v.x = fminf(fmaxf(rintf(v.x / s2), -128.f), 127.f) * s2;
        v.y = fminf(fmaxf(rintf(v.y / s2), -128.f), 127.f) * s2;
        v.z = fminf(fmaxf(rintf(v.z / s2), -128.f), 127.f) * s2;
        v.w = fminf(fmaxf(rintf(v.w / s2), -128.f), 127.f) * s2;
        o4[i] = v;
    }
    if (blockIdx.x == 0 && threadIdx.x == 0) out[N_OUT] = s2;
}

extern "C" void kernel_launch(void* const* d_in, const int* in_sizes, int n_in,
                              void* d_out, int out_size, void* d_ws, size_t ws_size,
                              hipStream_t stream) {
    const float* x      = (const float*)d_in[0];
    const float* conv_w = (const float*)d_in[1];
    const float* g      = (const float*)d_in[2];
    const float* beta   = (const float*)d_in[3];
    const float* mu     = (const float*)d_in[4];
    const float* var    = (const float*)d_in[5];
    float* out = (float*)d_out;

    char* wsb = (char*)d_ws;
    unsigned* cnt          = (unsigned*)wsb;
    float* b_int           = (float*)(wsb + 1024);
    float* scale_o         = (float*)(wsb + 2048);
    unsigned short* lut    = (unsigned short*)(wsb + 3072);
    unsigned short* w_q    = (unsigned short*)(wsb + 8192);
    short* pooledT         = (short*)(wsb + (1u << 20));

    hipMemsetAsync(cnt, 0, 16, stream);
    k_absmax_x<<<2048, 256, 0, stream>>>((const float4*)x, N_IN / 4, cnt);
    k_quant_pool<<<NG, 512, 0, stream>>>(x, pooledT, cnt);
    k_weights<<<O_ + 1, 256, 0, stream>>>(conv_w, g, beta, mu, var, cnt, w_q,
                                          b_int, scale_o, lut);
    dim3 ggrid(4, 1, B_);
    k_gemm<<<ggrid, 256, 0, stream>>>(pooledT, w_q, lut, b_int, scale_o, cnt, out);
    k_quant_out<<<2048, 256, 0, stream>>>(out, cnt);
}

// Round 9
// 155.320 us; speedup vs baseline: 1.6210x; 1.6210x over previous
//
#include <hip/hip_runtime.h>
#include <math.h>

#define B_    128
#define C_    768
#define O_    192
#define HW_   289
#define N_IN  (128*768*289)
#define N_OUT (128*192*289)
#define QN_   127.0f

// quant_pool: block = (b, kt) slab of 32 planes; padded LDS [32][19][20] f32
#define SLAB_E   (32*289)           // 9248 elements per slab
#define SLAB_SH  9248               // shorts per pooled slab
#define SLAB_BYT 18496              // bytes per pooled/xi slab
#define QP_LDS   (32*380)           // 12160 f32

typedef __attribute__((ext_vector_type(8))) short bf16x8;
typedef __attribute__((ext_vector_type(4))) float f32x4;

// XOR swizzle within a 64B row: flip 16B-chunk bits (4..5) by row bits (6..7). Involution.
#define SWZ(b) ((b) ^ ((((b) >> 6) & 3) << 4))

// ws layout:
//  0     : cnt[0]=absmax(x) bits, cnt[1]=max|pooled| int, cnt[2]=absmax(out) bits
//  1024  : f32 b_int[192]
//  2048  : f32 scale_o[192]
//  3072  : u16 lut[2305]
//  8192  : u16 w_q bf16 image, [kt][o][cc] linear, 24*6144 u16
//  1MiB  : i16 pooled[3072 slabs][289][32]  == later overwritten in-place as bf16 xi

__global__ void k_absmax_x(const float4* __restrict__ x4, int n4, unsigned* cnt) {
    float m = 0.f;
    for (int i = blockIdx.x * blockDim.x + threadIdx.x; i < n4;
         i += gridDim.x * blockDim.x) {
        float4 v = x4[i];
        m = fmaxf(m, fmaxf(fmaxf(fabsf(v.x), fabsf(v.y)),
                           fmaxf(fabsf(v.z), fabsf(v.w))));
    }
#pragma unroll
    for (int off = 32; off; off >>= 1) m = fmaxf(m, __shfl_down(m, off));
    __shared__ float sm[4];
    int lane = threadIdx.x & 63, wv = threadIdx.x >> 6;
    if (lane == 0) sm[wv] = m;
    __syncthreads();
    if (threadIdx.x == 0) {
        float bm = fmaxf(fmaxf(sm[0], sm[1]), fmaxf(sm[2], sm[3]));
        atomicMax(cnt + 0, __float_as_uint(bm));
    }
}

// Quantize + 3x3 zero-pad pooling. Block = (kt, b): 32 planes.
// Output layout: pooled[(b*24+kt)][hw][32] int16 — p-innermost lane map makes
// every wave store 2 full 64B lines.
__launch_bounds__(512) __global__
void k_quant_pool(const float* __restrict__ x, short* __restrict__ pooled,
                  unsigned* cnt) {
    __shared__ __align__(16) float fq[QP_LDS + 8];
    __shared__ int smax[8];
    const int tid = threadIdx.x;
    const int kt = blockIdx.x;          // 0..23
    const int b = blockIdx.z;           // 0..127
    const float s0 = fmaxf(__uint_as_float(cnt[0]) / QN_, 1e-8f);

    for (int i = tid; i < QP_LDS + 8; i += 512) fq[i] = 0.f;
    __syncthreads();

    // quant: float2 loads (slab base is 8B-aligned), padded scatter (p, r+1, c+1)
    const float2* xg2 = (const float2*)(x + ((size_t)b * 768 + kt * 32) * HW_);
    for (int t = tid; t < SLAB_E / 2; t += 512) {
        float2 v = xg2[t];
        int e = 2 * t;
#pragma unroll
        for (int j = 0; j < 2; ++j) {
            float xv = (j == 0) ? v.x : v.y;
            float q = fminf(fmaxf(rintf(xv / s0), -128.f), 127.f);
            int ej = e + j;
            int p = (int)(((long long)ej * 29027) >> 23);   // ej/289
            int i2 = ej - p * 289;
            int r = (i2 * 3856) >> 16;                      // i2/17
            int c = i2 - r * 17;
            fq[p * 380 + (r + 1) * 20 + (c + 1)] = q;
        }
    }
    __syncthreads();

    // pool: task = rt*32 + p, rt = r*5 + t5. 6 float4 taps -> 4 outputs.
    short* slab = pooled + (size_t)(b * 24 + kt) * SLAB_SH;
    int tmax = 0;
    for (int task = tid; task < 2720; task += 512) {
        int p = task & 31;
        int rt = task >> 5;                 // 0..84
        int r = (rt * 3277) >> 14;          // rt/5
        int t5 = rt - r * 5;
        int c0 = t5 * 4;
        const float* base = fq + p * 380 + r * 20 + c0;
        float4 a0 = *(const float4*)(base);
        float4 a1 = *(const float4*)(base + 4);
        float4 b0 = *(const float4*)(base + 20);
        float4 b1 = *(const float4*)(base + 24);
        float4 d0 = *(const float4*)(base + 40);
        float4 d1 = *(const float4*)(base + 44);
        float s0c = a0.x + b0.x + d0.x;
        float s1c = a0.y + b0.y + d0.y;
        float s2c = a0.z + b0.z + d0.z;
        float s3c = a0.w + b0.w + d0.w;
        float s4c = a1.x + b1.x + d1.x;
        float s5c = a1.y + b1.y + d1.y;
        int o0 = (int)(s0c + s1c + s2c);
        int o1 = (int)(s1c + s2c + s3c);
        int o2 = (int)(s2c + s3c + s4c);
        int o3 = (int)(s3c + s4c + s5c);
        int i0 = r * 17 + c0;
        slab[(i0 + 0) * 32 + p] = (short)o0;
        int a = o0 < 0 ? -o0 : o0; tmax = a > tmax ? a : tmax;
        if (c0 + 1 < 17) {
            slab[(i0 + 1) * 32 + p] = (short)o1;
            a = o1 < 0 ? -o1 : o1; tmax = a > tmax ? a : tmax;
            slab[(i0 + 2) * 32 + p] = (short)o2;
            a = o2 < 0 ? -o2 : o2; tmax = a > tmax ? a : tmax;
            slab[(i0 + 3) * 32 + p] = (short)o3;
            a = o3 < 0 ? -o3 : o3; tmax = a > tmax ? a : tmax;
        }
    }

#pragma unroll
    for (int off = 32; off; off >>= 1) {
        int o = __shfl_down(tmax, off);
        tmax = o > tmax ? o : tmax;
    }
    if ((tid & 63) == 0) smax[tid >> 6] = tmax;
    __syncthreads();
    if (tid == 0) {
        int bm = smax[0];
#pragma unroll
        for (int i = 1; i < 8; ++i) bm = smax[i] > bm ? smax[i] : bm;
        atomicMax((int*)(cnt + 1), bm);
    }
}

// BN-fold + per-channel weight quant -> bf16 image; block 192 computes the xi LUT.
__global__ void k_weights(const float* __restrict__ conv_w,
                          const float* __restrict__ g,
                          const float* __restrict__ beta,
                          const float* __restrict__ mu,
                          const float* __restrict__ var,
                          const unsigned* __restrict__ cnt,
                          unsigned short* __restrict__ w_q,
                          float* __restrict__ b_int, float* __restrict__ scale_o,
                          unsigned short* __restrict__ lut) {
    if (blockIdx.x == O_) {
        const float s0 = fmaxf(__uint_as_float(cnt[0]) / QN_, 1e-8f);
        const float maxx2 = ((float)((const int*)cnt)[1] / 9.0f) * s0;
        const float s1 = fmaxf(maxx2 / QN_, 1e-8f);
        for (int i = threadIdx.x; i < 2305; i += 256) {
            float p = (float)(i - 1152);
            float t = (p / 9.0f) * s0;
            float v = rintf(t / s1);
            v = fminf(fmaxf(v, -128.f), 127.f);
            lut[i] = (unsigned short)(__float_as_uint(v) >> 16);
        }
        return;
    }
    const int o = blockIdx.x;
    const float stdv = sqrtf(var[o] + 1e-5f);
    const float r = g[o] / stdv;
    const float* wo = conv_w + o * C_;
    float m = 0.f;
    for (int c = threadIdx.x; c < C_; c += 256) m = fmaxf(m, fabsf(wo[c] * r));
#pragma unroll
    for (int off = 32; off; off >>= 1) m = fmaxf(m, __shfl_down(m, off));
    __shared__ float sm[4];
    __shared__ float swsf;
    int lane = threadIdx.x & 63, wv = threadIdx.x >> 6;
    if (lane == 0) sm[wv] = m;
    __syncthreads();
    if (threadIdx.x == 0) {
        float bm = fmaxf(fmaxf(sm[0], sm[1]), fmaxf(sm[2], sm[3]));
        swsf = fmaxf(bm / QN_, 1e-8f);
    }
    __syncthreads();
    const float wsf = swsf;
    for (int c = threadIdx.x; c < C_; c += 256) {
        float wi = rintf(wo[c] * r / wsf);
        wi = fminf(fmaxf(wi, -128.f), 127.f);
        w_q[(c >> 5) * 6144 + o * 32 + (c & 31)] =
            (unsigned short)(__float_as_uint(wi) >> 16);
    }
    if (threadIdx.x == 0) {
        float s0 = fmaxf(__uint_as_float(cnt[0]) / QN_, 1e-8f);
        float maxx2 = ((float)((const int*)cnt)[1] / 9.0f) * s0;
        float s1 = fmaxf(maxx2 / QN_, 1e-8f);
        float bf = beta[o] - g[o] * mu[o] / stdv;
        b_int[o] = rintf(bf / (wsf * s1));
        scale_o[o] = wsf * s1;
    }
}

// Streaming in-place translate: pooled int16 -> xi bf16 via LUT (same buffer,
// element-wise). Hides LUT gathers under 114MB of HBM streaming.
__global__ void k_xi(unsigned* __restrict__ data,
                     const unsigned short* __restrict__ lut_g) {
    __shared__ unsigned short s_lut[2305];
    for (int i = threadIdx.x; i < 2305; i += 256) s_lut[i] = lut_g[i];
    __syncthreads();
    const int n2 = N_IN / 2;   // total uint (2 shorts each)
    uint2* d2 = (uint2*)data;
    for (int i = blockIdx.x * blockDim.x + threadIdx.x; i < n2 / 2;
         i += gridDim.x * blockDim.x) {
        uint2 v = d2[i];
        uint2 o;
        o.x = (unsigned)s_lut[1152 + (short)(v.x)] |
              ((unsigned)s_lut[1152 + (short)(v.x >> 16)] << 16);
        o.y = (unsigned)s_lut[1152 + (short)(v.y)] |
              ((unsigned)s_lut[1152 + (short)(v.y >> 16)] << 16);
        d2[i] = o;
    }
}

// MFMA GEMM: grid (4 hw, 1, 128 b) x 256 threads (4 waves of 48o x 80hw).
// Both W and X staged via global_load_lds (pre-swizzled source), double-buffered.
__launch_bounds__(256) __global__
void k_gemm(const unsigned short* __restrict__ xi,
            const unsigned short* __restrict__ w_q,
            const float* __restrict__ b_int, const float* __restrict__ scale_o,
            unsigned* cnt, float* __restrict__ out) {
    __shared__ char sW[2][12288];       // [192][32] bf16, XOR-swizzled
    __shared__ char sX[2][5120];        // [80][32] bf16 (hw rows), XOR-swizzled
    __shared__ float red[4];
    const int tid = threadIdx.x;
    const int b = blockIdx.z;
    const int hw0 = blockIdx.x * 80;
    const int L = tid & 63;
    const int wv = tid >> 6;
    const int wo = wv * 48;
    const char* xi_b = (const char*)xi;

    // per-lane X source offsets (row-clamped at 288), dest bases wave-uniform
    const int dA = wv * 1024 + L * 16;
    const int rowA = min(hw0 + (dA >> 6), HW_ - 1);
    const int offA = rowA * 64 + ((dA & 63) ^ (((dA >> 6) & 3) << 4));
    const int dB = 4096 + L * 16;
    const int rowB = min(hw0 + (dB >> 6), HW_ - 1);
    const int offB = rowB * 64 + ((dB & 63) ^ (((dB >> 6) & 3) << 4));

    auto stageW = [&](int kt, int buf) {
#pragma unroll
        for (int j = 0; j < 3; ++j) {
            int ldsoff = (wv * 3 + j) * 1024;
            const char* src = (const char*)w_q + kt * 12288 + SWZ(ldsoff + L * 16);
            __builtin_amdgcn_global_load_lds(
                (const __attribute__((address_space(1))) unsigned int*)src,
                (__attribute__((address_space(3))) unsigned int*)(&sW[buf][0] + ldsoff),
                16, 0, 0);
        }
    };
    auto stageX = [&](int kt, int buf) {
        size_t slab = (size_t)(b * 24 + kt) * SLAB_BYT;
        __builtin_amdgcn_global_load_lds(
            (const __attribute__((address_space(1))) unsigned int*)(xi_b + slab + offA),
            (__attribute__((address_space(3))) unsigned int*)(&sX[buf][0] + wv * 1024),
            16, 0, 0);
        if (wv == 0) {
            __builtin_amdgcn_global_load_lds(
                (const __attribute__((address_space(1))) unsigned int*)(xi_b + slab + offB),
                (__attribute__((address_space(3))) unsigned int*)(&sX[buf][0] + 4096),
                16, 0, 0);
        }
    };

    f32x4 acc[3][5] = {};

    stageW(0, 0);
    stageX(0, 0);
    __syncthreads();   // vmcnt drained -> buf0 ready

    for (int kt = 0; kt < 24; ++kt) {
        const int cur = kt & 1, nxt = cur ^ 1;
        if (kt < 23) {
            stageW(kt + 1, nxt);
            stageX(kt + 1, nxt);
        }
        bf16x8 af[3], bfr[5];
#pragma unroll
        for (int m = 0; m < 3; ++m)
            af[m] = *(const bf16x8*)(&sW[cur][0] +
                SWZ((wo + m * 16 + (L & 15)) * 64 + (L >> 4) * 16));
#pragma unroll
        for (int n = 0; n < 5; ++n)
            bfr[n] = *(const bf16x8*)(&sX[cur][0] +
                SWZ((n * 16 + (L & 15)) * 64 + (L >> 4) * 16));
#pragma unroll
        for (int m = 0; m < 3; ++m)
#pragma unroll
            for (int n = 0; n < 5; ++n)
                acc[m][n] = __builtin_amdgcn_mfma_f32_16x16x32_bf16(
                    af[m], bfr[n], acc[m][n], 0, 0, 0);
        __syncthreads();
    }

    float lmax = 0.f;
#pragma unroll
    for (int m = 0; m < 3; ++m) {
        int ob = wo + m * 16 + (L >> 4) * 4;
        float bi0 = b_int[ob + 0], bi1 = b_int[ob + 1];
        float bi2 = b_int[ob + 2], bi3 = b_int[ob + 3];
        float sc0 = scale_o[ob + 0], sc1 = scale_o[ob + 1];
        float sc2 = scale_o[ob + 2], sc3 = scale_o[ob + 3];
#pragma unroll
        for (int n = 0; n < 5; ++n) {
            int hw = hw0 + n * 16 + (L & 15);
            if (hw < HW_) {
                size_t base = ((size_t)b * O_ + ob) * HW_ + hw;
                float v0 = fmaxf((acc[m][n][0] + bi0) * sc0, 0.f);
                float v1 = fmaxf((acc[m][n][1] + bi1) * sc1, 0.f);
                float v2 = fmaxf((acc[m][n][2] + bi2) * sc2, 0.f);
                float v3 = fmaxf((acc[m][n][3] + bi3) * sc3, 0.f);
                out[base + 0 * HW_] = v0;
                out[base + 1 * HW_] = v1;
                out[base + 2 * HW_] = v2;
                out[base + 3 * HW_] = v3;
                lmax = fmaxf(fmaxf(fmaxf(v0, v1), fmaxf(v2, v3)), lmax);
            }
        }
    }
#pragma unroll
    for (int off = 32; off; off >>= 1) lmax = fmaxf(lmax, __shfl_down(lmax, off));
    if (L == 0) red[wv] = lmax;
    __syncthreads();
    if (tid == 0) {
        float bm = fmaxf(fmaxf(red[0], red[1]), fmaxf(red[2], red[3]));
        atomicMax(cnt + 2, __float_as_uint(bm));
    }
}

__global__ void k_quant_out(float* __restrict__ out, const unsigned* __restrict__ cnt) {
    const float s2 = fmaxf(__uint_as_float(cnt[2]) / QN_, 1e-8f);
    float4* o4 = (float4*)out;
    const int n4 = N_OUT / 4;
    for (int i = blockIdx.x * blockDim.x + threadIdx.x; i < n4;
         i += gridDim.x * blockDim.x) {
        float4 v = o4[i];
        v.x = fminf(fmaxf(rintf(v.x / s2), -128.f), 127.f) * s2;
        v.y = fminf(fmaxf(rintf(v.y / s2), -128.f), 127.f) * s2;
        v.z = fminf(fmaxf(rintf(v.z / s2), -128.f), 127.f) * s2;
        v.w = fminf(fmaxf(rintf(v.w / s2), -128.f), 127.f) * s2;
        o4[i] = v;
    }
    if (blockIdx.x == 0 && threadIdx.x == 0) out[N_OUT] = s2;
}

extern "C" void kernel_launch(void* const* d_in, const int* in_sizes, int n_in,
                              void* d_out, int out_size, void* d_ws, size_t ws_size,
                              hipStream_t stream) {
    const float* x      = (const float*)d_in[0];
    const float* conv_w = (const float*)d_in[1];
    const float* g      = (const float*)d_in[2];
    const float* beta   = (const float*)d_in[3];
    const float* mu     = (const float*)d_in[4];
    const float* var    = (const float*)d_in[5];
    float* out = (float*)d_out;

    char* wsb = (char*)d_ws;
    unsigned* cnt          = (unsigned*)wsb;
    float* b_int           = (float*)(wsb + 1024);
    float* scale_o         = (float*)(wsb + 2048);
    unsigned short* lut    = (unsigned short*)(wsb + 3072);
    unsigned short* w_q    = (unsigned short*)(wsb + 8192);
    short* pooled          = (short*)(wsb + (1u << 20));   // becomes xi bf16 in-place

    hipMemsetAsync(cnt, 0, 16, stream);
    k_absmax_x<<<2048, 256, 0, stream>>>((const float4*)x, N_IN / 4, cnt);
    dim3 qgrid(24, 1, B_);
    k_quant_pool<<<qgrid, 512, 0, stream>>>(x, pooled, cnt);
    k_weights<<<O_ + 1, 256, 0, stream>>>(conv_w, g, beta, mu, var, cnt, w_q,
                                          b_int, scale_o, lut);
    k_xi<<<2048, 256, 0, stream>>>((unsigned*)pooled, lut);
    dim3 ggrid(4, 1, B_);
    k_gemm<<<ggrid, 256, 0, stream>>>((const unsigned short*)pooled, w_q, b_int,
                                      scale_o, cnt, out);
    k_quant_out<<<2048, 256, 0, stream>>>(out, cnt);
}

// Round 10
// 152.849 us; speedup vs baseline: 1.6472x; 1.0162x over previous
//
#include <hip/hip_runtime.h>
#include <math.h>

#define B_    128
#define C_    768
#define O_    192
#define HW_   289
#define N_IN  (128*768*289)
#define N_OUT (128*192*289)
#define QN_   127.0f

// quant_pool: block = (b, kt) slab of 32 planes; padded LDS [32][19][20] f32
#define SLAB_E   (32*289)           // 9248 elements per slab
#define SLAB_SH  9248               // shorts per pooled slab
#define SLAB_BYT 18496              // bytes per pooled/xi slab
#define QP_LDS   (32*380)           // 12160 f32

typedef __attribute__((ext_vector_type(8))) short bf16x8;
typedef __attribute__((ext_vector_type(4))) float f32x4;

// XOR swizzle within a 64B row: flip 16B-chunk bits (4..5) by row bits (6..7). Involution.
#define SWZ(b) ((b) ^ ((((b) >> 6) & 3) << 4))

// ws layout:
//  0     : cnt[0]=absmax(x) bits, cnt[1]=max|pooled| int, cnt[2]=absmax(out) bits
//  1024  : f32 b_int[192]
//  2048  : f32 scale_o[192]
//  3072  : u16 lut[2305]
//  8192  : u16 w_q bf16 image, [kt][o][cc] linear, 24*6144 u16
//  1MiB  : i16 pooled[3072 slabs][289][32]  == later overwritten in-place as bf16 xi

__global__ void k_absmax_x(const float4* __restrict__ x4, int n4, unsigned* cnt) {
    float m = 0.f;
    const int stride = gridDim.x * blockDim.x;
    int i = blockIdx.x * blockDim.x + threadIdx.x;
    for (; i + stride < n4; i += 2 * stride) {
        float4 v = x4[i];
        float4 w = x4[i + stride];
        m = fmaxf(m, fmaxf(fmaxf(fabsf(v.x), fabsf(v.y)),
                           fmaxf(fabsf(v.z), fabsf(v.w))));
        m = fmaxf(m, fmaxf(fmaxf(fabsf(w.x), fabsf(w.y)),
                           fmaxf(fabsf(w.z), fabsf(w.w))));
    }
    if (i < n4) {
        float4 v = x4[i];
        m = fmaxf(m, fmaxf(fmaxf(fabsf(v.x), fabsf(v.y)),
                           fmaxf(fabsf(v.z), fabsf(v.w))));
    }
#pragma unroll
    for (int off = 32; off; off >>= 1) m = fmaxf(m, __shfl_down(m, off));
    __shared__ float sm[4];
    int lane = threadIdx.x & 63, wv = threadIdx.x >> 6;
    if (lane == 0) sm[wv] = m;
    __syncthreads();
    if (threadIdx.x == 0) {
        float bm = fmaxf(fmaxf(sm[0], sm[1]), fmaxf(sm[2], sm[3]));
        atomicMax(cnt + 0, __float_as_uint(bm));
    }
}

// Quantize + 3x3 zero-pad pooling. Block = (kt, b): 32 planes.
// Output layout: pooled[(b*24+kt)][hw][32] int16 — p-innermost lane map makes
// every wave store 2 full 64B lines.
__launch_bounds__(512) __global__
void k_quant_pool(const float* __restrict__ x, short* __restrict__ pooled,
                  unsigned* cnt) {
    __shared__ __align__(16) float fq[QP_LDS + 8];
    __shared__ int smax[8];
    const int tid = threadIdx.x;
    const int kt = blockIdx.x;          // 0..23
    const int b = blockIdx.z;           // 0..127
    const float s0 = fmaxf(__uint_as_float(cnt[0]) / QN_, 1e-8f);

    for (int i = tid; i < QP_LDS + 8; i += 512) fq[i] = 0.f;
    __syncthreads();

    // quant: float4 loads (slab base 16B-aligned), padded scatter (p, r+1, c+1).
    // No clamps: |x/s0| <= 127+eps so rintf stays in [-127,127].
    const float4* xg4 = (const float4*)(x + ((size_t)b * 768 + kt * 32) * HW_);
    for (int t = tid; t < SLAB_E / 4; t += 512) {
        float4 v = xg4[t];
        float q0 = rintf(v.x / s0);
        float q1 = rintf(v.y / s0);
        float q2 = rintf(v.z / s0);
        float q3 = rintf(v.w / s0);
        int e = 4 * t;
#pragma unroll
        for (int j = 0; j < 4; ++j) {
            float q = (j == 0) ? q0 : (j == 1) ? q1 : (j == 2) ? q2 : q3;
            int ej = e + j;
            int p = (ej * 29027) >> 23;            // ej/289 (ej<9248, fits 32b)
            int i2 = ej - p * 289;
            int r = (i2 * 3856) >> 16;             // i2/17
            int c = i2 - r * 17;
            fq[p * 380 + (r + 1) * 20 + (c + 1)] = q;
        }
    }
    __syncthreads();

    // pool: task = rt*32 + p, rt = r*5 + t5. 6 float4 taps -> 4 outputs.
    short* slab = pooled + (size_t)(b * 24 + kt) * SLAB_SH;
    int tmax = 0;
    for (int task = tid; task < 2720; task += 512) {
        int p = task & 31;
        int rt = task >> 5;                 // 0..84
        int r = (rt * 3277) >> 14;          // rt/5
        int t5 = rt - r * 5;
        int c0 = t5 * 4;
        const float* base = fq + p * 380 + r * 20 + c0;
        float4 a0 = *(const float4*)(base);
        float4 a1 = *(const float4*)(base + 4);
        float4 b0 = *(const float4*)(base + 20);
        float4 b1 = *(const float4*)(base + 24);
        float4 d0 = *(const float4*)(base + 40);
        float4 d1 = *(const float4*)(base + 44);
        float s0c = a0.x + b0.x + d0.x;
        float s1c = a0.y + b0.y + d0.y;
        float s2c = a0.z + b0.z + d0.z;
        float s3c = a0.w + b0.w + d0.w;
        float s4c = a1.x + b1.x + d1.x;
        float s5c = a1.y + b1.y + d1.y;
        int o0 = (int)(s0c + s1c + s2c);
        int o1 = (int)(s1c + s2c + s3c);
        int o2 = (int)(s2c + s3c + s4c);
        int o3 = (int)(s3c + s4c + s5c);
        int i0 = r * 17 + c0;
        slab[(i0 + 0) * 32 + p] = (short)o0;
        int a = o0 < 0 ? -o0 : o0; tmax = a > tmax ? a : tmax;
        if (c0 + 1 < 17) {
            slab[(i0 + 1) * 32 + p] = (short)o1;
            a = o1 < 0 ? -o1 : o1; tmax = a > tmax ? a : tmax;
            slab[(i0 + 2) * 32 + p] = (short)o2;
            a = o2 < 0 ? -o2 : o2; tmax = a > tmax ? a : tmax;
            slab[(i0 + 3) * 32 + p] = (short)o3;
            a = o3 < 0 ? -o3 : o3; tmax = a > tmax ? a : tmax;
        }
    }

#pragma unroll
    for (int off = 32; off; off >>= 1) {
        int o = __shfl_down(tmax, off);
        tmax = o > tmax ? o : tmax;
    }
    if ((tid & 63) == 0) smax[tid >> 6] = tmax;
    __syncthreads();
    if (tid == 0) {
        int bm = smax[0];
#pragma unroll
        for (int i = 1; i < 8; ++i) bm = smax[i] > bm ? smax[i] : bm;
        atomicMax((int*)(cnt + 1), bm);
    }
}

// BN-fold + per-channel weight quant -> bf16 image; block 192 computes the xi LUT.
__global__ void k_weights(const float* __restrict__ conv_w,
                          const float* __restrict__ g,
                          const float* __restrict__ beta,
                          const float* __restrict__ mu,
                          const float* __restrict__ var,
                          const unsigned* __restrict__ cnt,
                          unsigned short* __restrict__ w_q,
                          float* __restrict__ b_int, float* __restrict__ scale_o,
                          unsigned short* __restrict__ lut) {
    if (blockIdx.x == O_) {
        const float s0 = fmaxf(__uint_as_float(cnt[0]) / QN_, 1e-8f);
        const float maxx2 = ((float)((const int*)cnt)[1] / 9.0f) * s0;
        const float s1 = fmaxf(maxx2 / QN_, 1e-8f);
        for (int i = threadIdx.x; i < 2305; i += 256) {
            float p = (float)(i - 1152);
            float t = (p / 9.0f) * s0;
            float v = rintf(t / s1);
            v = fminf(fmaxf(v, -128.f), 127.f);
            lut[i] = (unsigned short)(__float_as_uint(v) >> 16);
        }
        return;
    }
    const int o = blockIdx.x;
    const float stdv = sqrtf(var[o] + 1e-5f);
    const float r = g[o] / stdv;
    const float* wo = conv_w + o * C_;
    float m = 0.f;
    for (int c = threadIdx.x; c < C_; c += 256) m = fmaxf(m, fabsf(wo[c] * r));
#pragma unroll
    for (int off = 32; off; off >>= 1) m = fmaxf(m, __shfl_down(m, off));
    __shared__ float sm[4];
    __shared__ float swsf;
    int lane = threadIdx.x & 63, wv = threadIdx.x >> 6;
    if (lane == 0) sm[wv] = m;
    __syncthreads();
    if (threadIdx.x == 0) {
        float bm = fmaxf(fmaxf(sm[0], sm[1]), fmaxf(sm[2], sm[3]));
        swsf = fmaxf(bm / QN_, 1e-8f);
    }
    __syncthreads();
    const float wsf = swsf;
    for (int c = threadIdx.x; c < C_; c += 256) {
        float wi = rintf(wo[c] * r / wsf);
        wi = fminf(fmaxf(wi, -128.f), 127.f);
        w_q[(c >> 5) * 6144 + o * 32 + (c & 31)] =
            (unsigned short)(__float_as_uint(wi) >> 16);
    }
    if (threadIdx.x == 0) {
        float s0 = fmaxf(__uint_as_float(cnt[0]) / QN_, 1e-8f);
        float maxx2 = ((float)((const int*)cnt)[1] / 9.0f) * s0;
        float s1 = fmaxf(maxx2 / QN_, 1e-8f);
        float bf = beta[o] - g[o] * mu[o] / stdv;
        b_int[o] = rintf(bf / (wsf * s1));
        scale_o[o] = wsf * s1;
    }
}

// Streaming in-place translate: pooled int16 -> xi bf16 via LUT (uint4 = 8 shorts/iter).
__global__ void k_xi(uint4* __restrict__ data,
                     const unsigned short* __restrict__ lut_g) {
    __shared__ unsigned short s_lut[2305];
    for (int i = threadIdx.x; i < 2305; i += 256) s_lut[i] = lut_g[i];
    __syncthreads();
    const int n4 = N_IN / 8;   // uint4 count (8 shorts each)
    for (int i = blockIdx.x * blockDim.x + threadIdx.x; i < n4;
         i += gridDim.x * blockDim.x) {
        uint4 v = data[i];
        uint4 o;
        o.x = (unsigned)s_lut[1152 + (short)(v.x)] |
              ((unsigned)s_lut[1152 + (short)(v.x >> 16)] << 16);
        o.y = (unsigned)s_lut[1152 + (short)(v.y)] |
              ((unsigned)s_lut[1152 + (short)(v.y >> 16)] << 16);
        o.z = (unsigned)s_lut[1152 + (short)(v.z)] |
              ((unsigned)s_lut[1152 + (short)(v.z >> 16)] << 16);
        o.w = (unsigned)s_lut[1152 + (short)(v.w)] |
              ((unsigned)s_lut[1152 + (short)(v.w >> 16)] << 16);
        data[i] = o;
    }
}

// MFMA GEMM: grid (4 hw, 1, 128 b) x 256 threads (4 waves of 48o x 80hw).
// Both W and X staged via global_load_lds (pre-swizzled source), double-buffered.
__launch_bounds__(256) __global__
void k_gemm(const unsigned short* __restrict__ xi,
            const unsigned short* __restrict__ w_q,
            const float* __restrict__ b_int, const float* __restrict__ scale_o,
            unsigned* cnt, float* __restrict__ out) {
    __shared__ char sW[2][12288];       // [192][32] bf16, XOR-swizzled
    __shared__ char sX[2][5120];        // [80][32] bf16 (hw rows), XOR-swizzled
    __shared__ float red[4];
    const int tid = threadIdx.x;
    const int b = blockIdx.z;
    const int hw0 = blockIdx.x * 80;
    const int L = tid & 63;
    const int wv = tid >> 6;
    const int wo = wv * 48;
    const char* xi_b = (const char*)xi;

    // per-lane X source offsets (row-clamped at 288), dest bases wave-uniform
    const int dA = wv * 1024 + L * 16;
    const int rowA = min(hw0 + (dA >> 6), HW_ - 1);
    const int offA = rowA * 64 + ((dA & 63) ^ (((dA >> 6) & 3) << 4));
    const int dB = 4096 + L * 16;
    const int rowB = min(hw0 + (dB >> 6), HW_ - 1);
    const int offB = rowB * 64 + ((dB & 63) ^ (((dB >> 6) & 3) << 4));

    auto stageW = [&](int kt, int buf) {
#pragma unroll
        for (int j = 0; j < 3; ++j) {
            int ldsoff = (wv * 3 + j) * 1024;
            const char* src = (const char*)w_q + kt * 12288 + SWZ(ldsoff + L * 16);
            __builtin_amdgcn_global_load_lds(
                (const __attribute__((address_space(1))) unsigned int*)src,
                (__attribute__((address_space(3))) unsigned int*)(&sW[buf][0] + ldsoff),
                16, 0, 0);
        }
    };
    auto stageX = [&](int kt, int buf) {
        size_t slab = (size_t)(b * 24 + kt) * SLAB_BYT;
        __builtin_amdgcn_global_load_lds(
            (const __attribute__((address_space(1))) unsigned int*)(xi_b + slab + offA),
            (__attribute__((address_space(3))) unsigned int*)(&sX[buf][0] + wv * 1024),
            16, 0, 0);
        if (wv == 0) {
            __builtin_amdgcn_global_load_lds(
                (const __attribute__((address_space(1))) unsigned int*)(xi_b + slab + offB),
                (__attribute__((address_space(3))) unsigned int*)(&sX[buf][0] + 4096),
                16, 0, 0);
        }
    };

    f32x4 acc[3][5] = {};

    stageW(0, 0);
    stageX(0, 0);
    __syncthreads();   // vmcnt drained -> buf0 ready

    for (int kt = 0; kt < 24; ++kt) {
        const int cur = kt & 1, nxt = cur ^ 1;
        if (kt < 23) {
            stageW(kt + 1, nxt);
            stageX(kt + 1, nxt);
        }
        bf16x8 af[3], bfr[5];
#pragma unroll
        for (int m = 0; m < 3; ++m)
            af[m] = *(const bf16x8*)(&sW[cur][0] +
                SWZ((wo + m * 16 + (L & 15)) * 64 + (L >> 4) * 16));
#pragma unroll
        for (int n = 0; n < 5; ++n)
            bfr[n] = *(const bf16x8*)(&sX[cur][0] +
                SWZ((n * 16 + (L & 15)) * 64 + (L >> 4) * 16));
#pragma unroll
        for (int m = 0; m < 3; ++m)
#pragma unroll
            for (int n = 0; n < 5; ++n)
                acc[m][n] = __builtin_amdgcn_mfma_f32_16x16x32_bf16(
                    af[m], bfr[n], acc[m][n], 0, 0, 0);
        __syncthreads();
    }

    float lmax = 0.f;
#pragma unroll
    for (int m = 0; m < 3; ++m) {
        int ob = wo + m * 16 + (L >> 4) * 4;
        float bi0 = b_int[ob + 0], bi1 = b_int[ob + 1];
        float bi2 = b_int[ob + 2], bi3 = b_int[ob + 3];
        float sc0 = scale_o[ob + 0], sc1 = scale_o[ob + 1];
        float sc2 = scale_o[ob + 2], sc3 = scale_o[ob + 3];
#pragma unroll
        for (int n = 0; n < 5; ++n) {
            int hw = hw0 + n * 16 + (L & 15);
            if (hw < HW_) {
                size_t base = ((size_t)b * O_ + ob) * HW_ + hw;
                float v0 = fmaxf((acc[m][n][0] + bi0) * sc0, 0.f);
                float v1 = fmaxf((acc[m][n][1] + bi1) * sc1, 0.f);
                float v2 = fmaxf((acc[m][n][2] + bi2) * sc2, 0.f);
                float v3 = fmaxf((acc[m][n][3] + bi3) * sc3, 0.f);
                out[base + 0 * HW_] = v0;
                out[base + 1 * HW_] = v1;
                out[base + 2 * HW_] = v2;
                out[base + 3 * HW_] = v3;
                lmax = fmaxf(fmaxf(fmaxf(v0, v1), fmaxf(v2, v3)), lmax);
            }
        }
    }
#pragma unroll
    for (int off = 32; off; off >>= 1) lmax = fmaxf(lmax, __shfl_down(lmax, off));
    if (L == 0) red[wv] = lmax;
    __syncthreads();
    if (tid == 0) {
        float bm = fmaxf(fmaxf(red[0], red[1]), fmaxf(red[2], red[3]));
        atomicMax(cnt + 2, __float_as_uint(bm));
    }
}

__global__ void k_quant_out(float* __restrict__ out, const unsigned* __restrict__ cnt) {
    const float s2 = fmaxf(__uint_as_float(cnt[2]) / QN_, 1e-8f);
    float4* o4 = (float4*)out;
    const int n4 = N_OUT / 4;
    for (int i = blockIdx.x * blockDim.x + threadIdx.x; i < n4;
         i += gridDim.x * blockDim.x) {
        float4 v = o4[i];
        v.x = fminf(fmaxf(rintf(v.x / s2), -128.f), 127.f) * s2;
        v.y = fminf(fmaxf(rintf(v.y / s2), -128.f), 127.f) * s2;
        v.z = fminf(fmaxf(rintf(v.z / s2), -128.f), 127.f) * s2;
        v.w = fminf(fmaxf(rintf(v.w / s2), -128.f), 127.f) * s2;
        o4[i] = v;
    }
    if (blockIdx.x == 0 && threadIdx.x == 0) out[N_OUT] = s2;
}

extern "C" void kernel_launch(void* const* d_in, const int* in_sizes, int n_in,
                              void* d_out, int out_size, void* d_ws, size_t ws_size,
                              hipStream_t stream) {
    const float* x      = (const float*)d_in[0];
    const float* conv_w = (const float*)d_in[1];
    const float* g      = (const float*)d_in[2];
    const float* beta   = (const float*)d_in[3];
    const float* mu     = (const float*)d_in[4];
    const float* var    = (const float*)d_in[5];
    float* out = (float*)d_out;

    char* wsb = (char*)d_ws;
    unsigned* cnt          = (unsigned*)wsb;
    float* b_int           = (float*)(wsb + 1024);
    float* scale_o         = (float*)(wsb + 2048);
    unsigned short* lut    = (unsigned short*)(wsb + 3072);
    unsigned short* w_q    = (unsigned short*)(wsb + 8192);
    short* pooled          = (short*)(wsb + (1u << 20));   // becomes xi bf16 in-place

    hipMemsetAsync(cnt, 0, 16, stream);
    k_absmax_x<<<2048, 256, 0, stream>>>((const float4*)x, N_IN / 4, cnt);
    dim3 qgrid(24, 1, B_);
    k_quant_pool<<<qgrid, 512, 0, stream>>>(x, pooled, cnt);
    k_weights<<<O_ + 1, 256, 0, stream>>>(conv_w, g, beta, mu, var, cnt, w_q,
                                          b_int, scale_o, lut);
    k_xi<<<2048, 256, 0, stream>>>((uint4*)pooled, lut);
    dim3 ggrid(4, 1, B_);
    k_gemm<<<ggrid, 256, 0, stream>>>((const unsigned short*)pooled, w_q, b_int,
                                      scale_o, cnt, out);
    k_quant_out<<<2048, 256, 0, stream>>>(out, cnt);
}

// Round 11
// 143.572 us; speedup vs baseline: 1.7536x; 1.0646x over previous
//
#include <hip/hip_runtime.h>
#include <math.h>

#define B_    128
#define C_    768
#define O_    192
#define HW_   289
#define N_IN  (128*768*289)
#define N_OUT (128*192*289)
#define QN_   127.0f

// quant_pool: block = (b, kt) slab of 32 planes; padded LDS [32][19][20] f32
#define SLAB_E   (32*289)           // 9248 elements per slab
#define SLAB_SH  9248               // shorts per pooled slab
#define SLAB_BYT 18496              // bytes per pooled slab
#define QP_LDS   (32*380)           // 12160 f32

typedef __attribute__((ext_vector_type(8))) short bf16x8;
typedef __attribute__((ext_vector_type(4))) float f32x4;

// XOR swizzle within a 64B row: flip 16B-chunk bits (4..5) by row bits (6..7). Involution.
#define SWZ(b) ((b) ^ ((((b) >> 6) & 3) << 4))

// ws layout:
//  0     : cnt[0]=absmax(x) bits, cnt[1]=max|pooled| int, cnt[2]=absmax(out) bits
//  1024  : f32 b_int[192]
//  2048  : f32 scale_o[192]
//  3072  : u16 lut[2305]
//  8192  : u16 w_q bf16 image, [kt][o][cc] linear, 24*6144 u16
//  1MiB  : i16 pooled[3072 slabs][289][32]

__global__ void k_absmax_x(const float4* __restrict__ x4, int n4, unsigned* cnt) {
    float m = 0.f;
    const int stride = gridDim.x * blockDim.x;
    int i = blockIdx.x * blockDim.x + threadIdx.x;
    for (; i + stride < n4; i += 2 * stride) {
        float4 v = x4[i];
        float4 w = x4[i + stride];
        m = fmaxf(m, fmaxf(fmaxf(fabsf(v.x), fabsf(v.y)),
                           fmaxf(fabsf(v.z), fabsf(v.w))));
        m = fmaxf(m, fmaxf(fmaxf(fabsf(w.x), fabsf(w.y)),
                           fmaxf(fabsf(w.z), fabsf(w.w))));
    }
    if (i < n4) {
        float4 v = x4[i];
        m = fmaxf(m, fmaxf(fmaxf(fabsf(v.x), fabsf(v.y)),
                           fmaxf(fabsf(v.z), fabsf(v.w))));
    }
#pragma unroll
    for (int off = 32; off; off >>= 1) m = fmaxf(m, __shfl_down(m, off));
    __shared__ float sm[4];
    int lane = threadIdx.x & 63, wv = threadIdx.x >> 6;
    if (lane == 0) sm[wv] = m;
    __syncthreads();
    if (threadIdx.x == 0) {
        float bm = fmaxf(fmaxf(sm[0], sm[1]), fmaxf(sm[2], sm[3]));
        atomicMax(cnt + 0, __float_as_uint(bm));
    }
}

// Quantize + 3x3 zero-pad pooling. Block = (kt, b): 32 planes.
// Output layout: pooled[(b*24+kt)][hw][32] int16.
__launch_bounds__(512) __global__
void k_quant_pool(const float* __restrict__ x, short* __restrict__ pooled,
                  unsigned* cnt) {
    __shared__ __align__(16) float fq[QP_LDS + 8];
    __shared__ int smax[8];
    const int tid = threadIdx.x;
    const int kt = blockIdx.x;          // 0..23
    const int b = blockIdx.z;           // 0..127
    const float s0 = fmaxf(__uint_as_float(cnt[0]) / QN_, 1e-8f);

    for (int i = tid; i < QP_LDS + 8; i += 512) fq[i] = 0.f;
    __syncthreads();

    const float4* xg4 = (const float4*)(x + ((size_t)b * 768 + kt * 32) * HW_);
    for (int t = tid; t < SLAB_E / 4; t += 512) {
        float4 v = xg4[t];
        float q0 = rintf(v.x / s0);
        float q1 = rintf(v.y / s0);
        float q2 = rintf(v.z / s0);
        float q3 = rintf(v.w / s0);
        int e = 4 * t;
#pragma unroll
        for (int j = 0; j < 4; ++j) {
            float q = (j == 0) ? q0 : (j == 1) ? q1 : (j == 2) ? q2 : q3;
            int ej = e + j;
            int p = (ej * 29027) >> 23;            // ej/289
            int i2 = ej - p * 289;
            int r = (i2 * 3856) >> 16;             // i2/17
            int c = i2 - r * 17;
            fq[p * 380 + (r + 1) * 20 + (c + 1)] = q;
        }
    }
    __syncthreads();

    short* slab = pooled + (size_t)(b * 24 + kt) * SLAB_SH;
    int tmax = 0;
    for (int task = tid; task < 2720; task += 512) {
        int p = task & 31;
        int rt = task >> 5;                 // 0..84
        int r = (rt * 3277) >> 14;          // rt/5
        int t5 = rt - r * 5;
        int c0 = t5 * 4;
        const float* base = fq + p * 380 + r * 20 + c0;
        float4 a0 = *(const float4*)(base);
        float4 a1 = *(const float4*)(base + 4);
        float4 b0 = *(const float4*)(base + 20);
        float4 b1 = *(const float4*)(base + 24);
        float4 d0 = *(const float4*)(base + 40);
        float4 d1 = *(const float4*)(base + 44);
        float s0c = a0.x + b0.x + d0.x;
        float s1c = a0.y + b0.y + d0.y;
        float s2c = a0.z + b0.z + d0.z;
        float s3c = a0.w + b0.w + d0.w;
        float s4c = a1.x + b1.x + d1.x;
        float s5c = a1.y + b1.y + d1.y;
        int o0 = (int)(s0c + s1c + s2c);
        int o1 = (int)(s1c + s2c + s3c);
        int o2 = (int)(s2c + s3c + s4c);
        int o3 = (int)(s3c + s4c + s5c);
        int i0 = r * 17 + c0;
        slab[(i0 + 0) * 32 + p] = (short)o0;
        int a = o0 < 0 ? -o0 : o0; tmax = a > tmax ? a : tmax;
        if (c0 + 1 < 17) {
            slab[(i0 + 1) * 32 + p] = (short)o1;
            a = o1 < 0 ? -o1 : o1; tmax = a > tmax ? a : tmax;
            slab[(i0 + 2) * 32 + p] = (short)o2;
            a = o2 < 0 ? -o2 : o2; tmax = a > tmax ? a : tmax;
            slab[(i0 + 3) * 32 + p] = (short)o3;
            a = o3 < 0 ? -o3 : o3; tmax = a > tmax ? a : tmax;
        }
    }

#pragma unroll
    for (int off = 32; off; off >>= 1) {
        int o = __shfl_down(tmax, off);
        tmax = o > tmax ? o : tmax;
    }
    if ((tid & 63) == 0) smax[tid >> 6] = tmax;
    __syncthreads();
    if (tid == 0) {
        int bm = smax[0];
#pragma unroll
        for (int i = 1; i < 8; ++i) bm = smax[i] > bm ? smax[i] : bm;
        atomicMax((int*)(cnt + 1), bm);
    }
}

// BN-fold + per-channel weight quant -> bf16 image; block 192 computes the xi LUT.
__global__ void k_weights(const float* __restrict__ conv_w,
                          const float* __restrict__ g,
                          const float* __restrict__ beta,
                          const float* __restrict__ mu,
                          const float* __restrict__ var,
                          const unsigned* __restrict__ cnt,
                          unsigned short* __restrict__ w_q,
                          float* __restrict__ b_int, float* __restrict__ scale_o,
                          unsigned short* __restrict__ lut) {
    if (blockIdx.x == O_) {
        const float s0 = fmaxf(__uint_as_float(cnt[0]) / QN_, 1e-8f);
        const float maxx2 = ((float)((const int*)cnt)[1] / 9.0f) * s0;
        const float s1 = fmaxf(maxx2 / QN_, 1e-8f);
        for (int i = threadIdx.x; i < 2305; i += 256) {
            float p = (float)(i - 1152);
            float t = (p / 9.0f) * s0;
            float v = rintf(t / s1);
            v = fminf(fmaxf(v, -128.f), 127.f);
            lut[i] = (unsigned short)(__float_as_uint(v) >> 16);
        }
        return;
    }
    const int o = blockIdx.x;
    const float stdv = sqrtf(var[o] + 1e-5f);
    const float r = g[o] / stdv;
    const float* wo = conv_w + o * C_;
    float m = 0.f;
    for (int c = threadIdx.x; c < C_; c += 256) m = fmaxf(m, fabsf(wo[c] * r));
#pragma unroll
    for (int off = 32; off; off >>= 1) m = fmaxf(m, __shfl_down(m, off));
    __shared__ float sm[4];
    __shared__ float swsf;
    int lane = threadIdx.x & 63, wv = threadIdx.x >> 6;
    if (lane == 0) sm[wv] = m;
    __syncthreads();
    if (threadIdx.x == 0) {
        float bm = fmaxf(fmaxf(sm[0], sm[1]), fmaxf(sm[2], sm[3]));
        swsf = fmaxf(bm / QN_, 1e-8f);
    }
    __syncthreads();
    const float wsf = swsf;
    for (int c = threadIdx.x; c < C_; c += 256) {
        float wi = rintf(wo[c] * r / wsf);
        wi = fminf(fmaxf(wi, -128.f), 127.f);
        w_q[(c >> 5) * 6144 + o * 32 + (c & 31)] =
            (unsigned short)(__float_as_uint(wi) >> 16);
    }
    if (threadIdx.x == 0) {
        float s0 = fmaxf(__uint_as_float(cnt[0]) / QN_, 1e-8f);
        float maxx2 = ((float)((const int*)cnt)[1] / 9.0f) * s0;
        float s1 = fmaxf(maxx2 / QN_, 1e-8f);
        float bf = beta[o] - g[o] * mu[o] / stdv;
        b_int[o] = rintf(bf / (wsf * s1));
        scale_o[o] = wsf * s1;
    }
}

// MFMA GEMM: grid (4 hw, 1, 128 b) x 256 threads (4 waves of 48o x 80hw).
// W staged via global_load_lds; X staged reg->LUT->LDS from int16 slabs
// (coalesced uint4 loads). Double-buffered, one barrier per K-step.
__launch_bounds__(256) __global__
void k_gemm(const short* __restrict__ pooled,
            const unsigned short* __restrict__ w_q,
            const unsigned short* __restrict__ lut_g,
            const float* __restrict__ b_int, const float* __restrict__ scale_o,
            unsigned* cnt, float* __restrict__ out) {
    __shared__ char sW[2][12288];       // [192][32] bf16, XOR-swizzled
    __shared__ char sX[2][5120];        // [80][32] bf16 (hw rows), XOR-swizzled
    __shared__ unsigned short s_lut[2305];
    __shared__ float red[4];
    const int tid = threadIdx.x;
    const int b = blockIdx.z;
    const int hw0 = blockIdx.x * 80;
    const int L = tid & 63;
    const int wv = tid >> 6;
    const int wo = wv * 48;
    const char* pooled_b = (const char*)pooled;

    for (int i = tid; i < 2305; i += 256) s_lut[i] = lut_g[i];

    // X staging: item = (hwr, cg) with item0 = tid -> hwr=tid>>2, cg=tid&3
    // (consecutive lanes = consecutive 16B chunks -> coalesced), item1 = 256+tid (tid<64).
    const int hwr0 = tid >> 2, cg0 = tid & 3;
    const int hwr1 = 64 + (tid >> 2), cg1 = tid & 3;
    const bool act1 = tid < 64;
    const int hwg0 = hw0 + hwr0, hwg1 = hw0 + hwr1;

    uint4 xr0, xr1;

    auto stageW = [&](int kt, int buf) {
#pragma unroll
        for (int j = 0; j < 3; ++j) {
            int ldsoff = (wv * 3 + j) * 1024;
            const char* src = (const char*)w_q + kt * 12288 + SWZ(ldsoff + L * 16);
            __builtin_amdgcn_global_load_lds(
                (const __attribute__((address_space(1))) unsigned int*)src,
                (__attribute__((address_space(3))) unsigned int*)(&sW[buf][0] + ldsoff),
                16, 0, 0);
        }
    };
    auto loadX = [&](int kt) {
        uint4 z; z.x = z.y = z.z = z.w = 0u;
        size_t slab = (size_t)(b * 24 + kt) * SLAB_BYT;
        xr0 = (hwg0 < HW_)
            ? *(const uint4*)(pooled_b + slab + hwg0 * 64 + cg0 * 16) : z;
        if (act1)
            xr1 = (hwg1 < HW_)
                ? *(const uint4*)(pooled_b + slab + hwg1 * 64 + cg1 * 16) : z;
    };
    auto writeX = [&](int buf) {
        uint4 q;
        q.x = (unsigned)s_lut[1152 + (short)(xr0.x)] |
              ((unsigned)s_lut[1152 + (short)(xr0.x >> 16)] << 16);
        q.y = (unsigned)s_lut[1152 + (short)(xr0.y)] |
              ((unsigned)s_lut[1152 + (short)(xr0.y >> 16)] << 16);
        q.z = (unsigned)s_lut[1152 + (short)(xr0.z)] |
              ((unsigned)s_lut[1152 + (short)(xr0.z >> 16)] << 16);
        q.w = (unsigned)s_lut[1152 + (short)(xr0.w)] |
              ((unsigned)s_lut[1152 + (short)(xr0.w >> 16)] << 16);
        *(uint4*)(&sX[buf][0] + SWZ(hwr0 * 64 + cg0 * 16)) = q;
        if (act1) {
            uint4 p2;
            p2.x = (unsigned)s_lut[1152 + (short)(xr1.x)] |
                   ((unsigned)s_lut[1152 + (short)(xr1.x >> 16)] << 16);
            p2.y = (unsigned)s_lut[1152 + (short)(xr1.y)] |
                   ((unsigned)s_lut[1152 + (short)(xr1.y >> 16)] << 16);
            p2.z = (unsigned)s_lut[1152 + (short)(xr1.z)] |
                   ((unsigned)s_lut[1152 + (short)(xr1.z >> 16)] << 16);
            p2.w = (unsigned)s_lut[1152 + (short)(xr1.w)] |
                   ((unsigned)s_lut[1152 + (short)(xr1.w >> 16)] << 16);
            *(uint4*)(&sX[buf][0] + SWZ(hwr1 * 64 + cg1 * 16)) = p2;
        }
    };

    f32x4 acc[3][5] = {};

    stageW(0, 0);
    loadX(0);
    __syncthreads();   // s_lut ready (also drains W(0))
    writeX(0);
    __syncthreads();   // buf0 ready

    for (int kt = 0; kt < 24; ++kt) {
        const int cur = kt & 1, nxt = cur ^ 1;
        if (kt < 23) {
            stageW(kt + 1, nxt);
            loadX(kt + 1);
        }
        bf16x8 af[3], bfr[5];
#pragma unroll
        for (int m = 0; m < 3; ++m)
            af[m] = *(const bf16x8*)(&sW[cur][0] +
                SWZ((wo + m * 16 + (L & 15)) * 64 + (L >> 4) * 16));
#pragma unroll
        for (int n = 0; n < 5; ++n)
            bfr[n] = *(const bf16x8*)(&sX[cur][0] +
                SWZ((n * 16 + (L & 15)) * 64 + (L >> 4) * 16));
#pragma unroll
        for (int m = 0; m < 3; ++m)
#pragma unroll
            for (int n = 0; n < 5; ++n)
                acc[m][n] = __builtin_amdgcn_mfma_f32_16x16x32_bf16(
                    af[m], bfr[n], acc[m][n], 0, 0, 0);
        if (kt < 23) writeX(nxt);
        __syncthreads();
    }

    float lmax = 0.f;
#pragma unroll
    for (int m = 0; m < 3; ++m) {
        int ob = wo + m * 16 + (L >> 4) * 4;
        float bi0 = b_int[ob + 0], bi1 = b_int[ob + 1];
        float bi2 = b_int[ob + 2], bi3 = b_int[ob + 3];
        float sc0 = scale_o[ob + 0], sc1 = scale_o[ob + 1];
        float sc2 = scale_o[ob + 2], sc3 = scale_o[ob + 3];
#pragma unroll
        for (int n = 0; n < 5; ++n) {
            int hw = hw0 + n * 16 + (L & 15);
            if (hw < HW_) {
                size_t base = ((size_t)b * O_ + ob) * HW_ + hw;
                float v0 = fmaxf((acc[m][n][0] + bi0) * sc0, 0.f);
                float v1 = fmaxf((acc[m][n][1] + bi1) * sc1, 0.f);
                float v2 = fmaxf((acc[m][n][2] + bi2) * sc2, 0.f);
                float v3 = fmaxf((acc[m][n][3] + bi3) * sc3, 0.f);
                out[base + 0 * HW_] = v0;
                out[base + 1 * HW_] = v1;
                out[base + 2 * HW_] = v2;
                out[base + 3 * HW_] = v3;
                lmax = fmaxf(fmaxf(fmaxf(v0, v1), fmaxf(v2, v3)), lmax);
            }
        }
    }
#pragma unroll
    for (int off = 32; off; off >>= 1) lmax = fmaxf(lmax, __shfl_down(lmax, off));
    if (L == 0) red[wv] = lmax;
    __syncthreads();
    if (tid == 0) {
        float bm = fmaxf(fmaxf(red[0], red[1]), fmaxf(red[2], red[3]));
        atomicMax(cnt + 2, __float_as_uint(bm));
    }
}

__global__ void k_quant_out(float* __restrict__ out, const unsigned* __restrict__ cnt) {
    const float s2 = fmaxf(__uint_as_float(cnt[2]) / QN_, 1e-8f);
    float4* o4 = (float4*)out;
    const int n4 = N_OUT / 4;
    for (int i = blockIdx.x * blockDim.x + threadIdx.x; i < n4;
         i += gridDim.x * blockDim.x) {
        float4 v = o4[i];
        v.x = fminf(fmaxf(rintf(v.x / s2), -128.f), 127.f) * s2;
        v.y = fminf(fmaxf(rintf(v.y / s2), -128.f), 127.f) * s2;
        v.z = fminf(fmaxf(rintf(v.z / s2), -128.f), 127.f) * s2;
        v.w = fminf(fmaxf(rintf(v.w / s2), -128.f), 127.f) * s2;
        o4[i] = v;
    }
    if (blockIdx.x == 0 && threadIdx.x == 0) out[N_OUT] = s2;
}

extern "C" void kernel_launch(void* const* d_in, const int* in_sizes, int n_in,
                              void* d_out, int out_size, void* d_ws, size_t ws_size,
                              hipStream_t stream) {
    const float* x      = (const float*)d_in[0];
    const float* conv_w = (const float*)d_in[1];
    const float* g      = (const float*)d_in[2];
    const float* beta   = (const float*)d_in[3];
    const float* mu     = (const float*)d_in[4];
    const float* var    = (const float*)d_in[5];
    float* out = (float*)d_out;

    char* wsb = (char*)d_ws;
    unsigned* cnt          = (unsigned*)wsb;
    float* b_int           = (float*)(wsb + 1024);
    float* scale_o         = (float*)(wsb + 2048);
    unsigned short* lut    = (unsigned short*)(wsb + 3072);
    unsigned short* w_q    = (unsigned short*)(wsb + 8192);
    short* pooled          = (short*)(wsb + (1u << 20));

    hipMemsetAsync(cnt, 0, 16, stream);
    k_absmax_x<<<2048, 256, 0, stream>>>((const float4*)x, N_IN / 4, cnt);
    dim3 qgrid(24, 1, B_);
    k_quant_pool<<<qgrid, 512, 0, stream>>>(x, pooled, cnt);
    k_weights<<<O_ + 1, 256, 0, stream>>>(conv_w, g, beta, mu, var, cnt, w_q,
                                          b_int, scale_o, lut);
    dim3 ggrid(4, 1, B_);
    k_gemm<<<ggrid, 256, 0, stream>>>(pooled, w_q, lut, b_int, scale_o, cnt, out);
    k_quant_out<<<2048, 256, 0, stream>>>(out, cnt);
}

// Round 14
// 132.274 us; speedup vs baseline: 1.9034x; 1.0854x over previous
//
#include <hip/hip_runtime.h>
#include <math.h>

#define B_    128
#define C_    768
#define O_    192
#define HW_   289
#define N_IN  (128*768*289)
#define N_OUT (128*192*289)
#define QN_   127.0f

// quant_pool: block = (b, kt32) slab of 32 planes; padded LDS [32][19][20] f32
#define SLAB_E   (32*289)           // 9248 elements per slab
#define SLAB_SH  9248               // shorts per pooled slab
#define SLAB_BYT 18496              // bytes per pooled slab
#define QP_LDS   (32*380)           // 12160 f32

typedef __attribute__((ext_vector_type(4))) int i32x4;

// XOR swizzle within a 64B row: flip 16B-chunk bits (4..5) by row bits (6..7). Involution.
#define SWZ(b) ((b) ^ ((((b) >> 6) & 3) << 4))

// ws layout:
//  0     : cnt[0]=absmax(x) bits, cnt[1]=max|pooled| int, cnt[2]=absmax(out) bits
//  1024  : f32 b_int[192]
//  2048  : f32 scale_o[192]
//  3072  : u8 lut8[2305]  (int8 xi codes)
//  8192  : i8 w_q8 image, [kt64][o][64c] linear, 12*12288 B
//  1MiB  : i16 pooled[3072 slabs][289][32]

__global__ void k_absmax_x(const float4* __restrict__ x4, int n4, unsigned* cnt) {
    float m = 0.f;
    const int stride = gridDim.x * blockDim.x;
    int i = blockIdx.x * blockDim.x + threadIdx.x;
    for (; i + stride < n4; i += 2 * stride) {
        float4 v = x4[i];
        float4 w = x4[i + stride];
        m = fmaxf(m, fmaxf(fmaxf(fabsf(v.x), fabsf(v.y)),
                           fmaxf(fabsf(v.z), fabsf(v.w))));
        m = fmaxf(m, fmaxf(fmaxf(fabsf(w.x), fabsf(w.y)),
                           fmaxf(fabsf(w.z), fabsf(w.w))));
    }
    if (i < n4) {
        float4 v = x4[i];
        m = fmaxf(m, fmaxf(fmaxf(fabsf(v.x), fabsf(v.y)),
                           fmaxf(fabsf(v.z), fabsf(v.w))));
    }
#pragma unroll
    for (int off = 32; off; off >>= 1) m = fmaxf(m, __shfl_down(m, off));
    __shared__ float sm[4];
    int lane = threadIdx.x & 63, wv = threadIdx.x >> 6;
    if (lane == 0) sm[wv] = m;
    __syncthreads();
    if (threadIdx.x == 0) {
        float bm = fmaxf(fmaxf(sm[0], sm[1]), fmaxf(sm[2], sm[3]));
        atomicMax(cnt + 0, __float_as_uint(bm));
    }
}

// Quantize + 3x3 zero-pad pooling. Block = (kt32, b): 32 planes.
// Output layout: pooled[(b*24+kt32)][hw][32] int16.
__launch_bounds__(512) __global__
void k_quant_pool(const float* __restrict__ x, short* __restrict__ pooled,
                  unsigned* cnt) {
    __shared__ __align__(16) float fq[QP_LDS + 8];
    __shared__ int smax[8];
    const int tid = threadIdx.x;
    const int kt = blockIdx.x;          // 0..23
    const int b = blockIdx.z;           // 0..127
    const float s0 = fmaxf(__uint_as_float(cnt[0]) / QN_, 1e-8f);

    for (int i = tid; i < QP_LDS + 8; i += 512) fq[i] = 0.f;
    __syncthreads();

    const float4* xg4 = (const float4*)(x + ((size_t)b * 768 + kt * 32) * HW_);
    for (int t = tid; t < SLAB_E / 4; t += 512) {
        float4 v = xg4[t];
        float q0 = rintf(v.x / s0);
        float q1 = rintf(v.y / s0);
        float q2 = rintf(v.z / s0);
        float q3 = rintf(v.w / s0);
        int e = 4 * t;
#pragma unroll
        for (int j = 0; j < 4; ++j) {
            float q = (j == 0) ? q0 : (j == 1) ? q1 : (j == 2) ? q2 : q3;
            int ej = e + j;
            int p = (ej * 29027) >> 23;            // ej/289
            int i2 = ej - p * 289;
            int r = (i2 * 3856) >> 16;             // i2/17
            int c = i2 - r * 17;
            fq[p * 380 + (r + 1) * 20 + (c + 1)] = q;
        }
    }
    __syncthreads();

    short* slab = pooled + (size_t)(b * 24 + kt) * SLAB_SH;
    int tmax = 0;
    for (int task = tid; task < 2720; task += 512) {
        int p = task & 31;
        int rt = task >> 5;                 // 0..84
        int r = (rt * 3277) >> 14;          // rt/5
        int t5 = rt - r * 5;
        int c0 = t5 * 4;
        const float* base = fq + p * 380 + r * 20 + c0;
        float4 a0 = *(const float4*)(base);
        float4 a1 = *(const float4*)(base + 4);
        float4 b0 = *(const float4*)(base + 20);
        float4 b1 = *(const float4*)(base + 24);
        float4 d0 = *(const float4*)(base + 40);
        float4 d1 = *(const float4*)(base + 44);
        float s0c = a0.x + b0.x + d0.x;
        float s1c = a0.y + b0.y + d0.y;
        float s2c = a0.z + b0.z + d0.z;
        float s3c = a0.w + b0.w + d0.w;
        float s4c = a1.x + b1.x + d1.x;
        float s5c = a1.y + b1.y + d1.y;
        int o0 = (int)(s0c + s1c + s2c);
        int o1 = (int)(s1c + s2c + s3c);
        int o2 = (int)(s2c + s3c + s4c);
        int o3 = (int)(s3c + s4c + s5c);
        int i0 = r * 17 + c0;
        slab[(i0 + 0) * 32 + p] = (short)o0;
        int a = o0 < 0 ? -o0 : o0; tmax = a > tmax ? a : tmax;
        if (c0 + 1 < 17) {
            slab[(i0 + 1) * 32 + p] = (short)o1;
            a = o1 < 0 ? -o1 : o1; tmax = a > tmax ? a : tmax;
            slab[(i0 + 2) * 32 + p] = (short)o2;
            a = o2 < 0 ? -o2 : o2; tmax = a > tmax ? a : tmax;
            slab[(i0 + 3) * 32 + p] = (short)o3;
            a = o3 < 0 ? -o3 : o3; tmax = a > tmax ? a : tmax;
        }
    }

#pragma unroll
    for (int off = 32; off; off >>= 1) {
        int o = __shfl_down(tmax, off);
        tmax = o > tmax ? o : tmax;
    }
    if ((tid & 63) == 0) smax[tid >> 6] = tmax;
    __syncthreads();
    if (tid == 0) {
        int bm = smax[0];
#pragma unroll
        for (int i = 1; i < 8; ++i) bm = smax[i] > bm ? smax[i] : bm;
        atomicMax((int*)(cnt + 1), bm);
    }
}

// BN-fold + per-channel weight quant -> int8 image [kt64][o][64c]; block 192: int8 xi LUT.
__global__ void k_weights(const float* __restrict__ conv_w,
                          const float* __restrict__ g,
                          const float* __restrict__ beta,
                          const float* __restrict__ mu,
                          const float* __restrict__ var,
                          const unsigned* __restrict__ cnt,
                          signed char* __restrict__ w_q8,
                          float* __restrict__ b_int, float* __restrict__ scale_o,
                          unsigned char* __restrict__ lut8) {
    if (blockIdx.x == O_) {
        const float s0 = fmaxf(__uint_as_float(cnt[0]) / QN_, 1e-8f);
        const float maxx2 = ((float)((const int*)cnt)[1] / 9.0f) * s0;
        const float s1 = fmaxf(maxx2 / QN_, 1e-8f);
        for (int i = threadIdx.x; i < 2305; i += 256) {
            float p = (float)(i - 1152);
            float t = (p / 9.0f) * s0;
            float v = rintf(t / s1);
            v = fminf(fmaxf(v, -128.f), 127.f);
            lut8[i] = (unsigned char)(signed char)(int)v;
        }
        return;
    }
    const int o = blockIdx.x;
    const float stdv = sqrtf(var[o] + 1e-5f);
    const float r = g[o] / stdv;
    const float* wo = conv_w + o * C_;
    float m = 0.f;
    for (int c = threadIdx.x; c < C_; c += 256) m = fmaxf(m, fabsf(wo[c] * r));
#pragma unroll
    for (int off = 32; off; off >>= 1) m = fmaxf(m, __shfl_down(m, off));
    __shared__ float sm[4];
    __shared__ float swsf;
    int lane = threadIdx.x & 63, wv = threadIdx.x >> 6;
    if (lane == 0) sm[wv] = m;
    __syncthreads();
    if (threadIdx.x == 0) {
        float bm = fmaxf(fmaxf(sm[0], sm[1]), fmaxf(sm[2], sm[3]));
        swsf = fmaxf(bm / QN_, 1e-8f);
    }
    __syncthreads();
    const float wsf = swsf;
    for (int c = threadIdx.x; c < C_; c += 256) {
        float wi = rintf(wo[c] * r / wsf);
        wi = fminf(fmaxf(wi, -128.f), 127.f);
        w_q8[(c >> 6) * 12288 + o * 64 + (c & 63)] = (signed char)(int)wi;
    }
    if (threadIdx.x == 0) {
        float s0 = fmaxf(__uint_as_float(cnt[0]) / QN_, 1e-8f);
        float maxx2 = ((float)((const int*)cnt)[1] / 9.0f) * s0;
        float s1 = fmaxf(maxx2 / QN_, 1e-8f);
        float bf = beta[o] - g[o] * mu[o] / stdv;
        b_int[o] = rintf(bf / (wsf * s1));
        scale_o[o] = wsf * s1;
    }
}

// int8 MFMA GEMM: grid (4 hw, 1, 128 b) x 256 threads (4 waves of 48o x 80hw).
// K=64 per step -> 12 iterations. W via global_load_lds (int8, pre-swizzled src);
// X staged reg->LUT->int8 LDS from int16 slabs. Double-buffered, 1 barrier/K-step.
__launch_bounds__(256) __global__
void k_gemm(const short* __restrict__ pooled,
            const signed char* __restrict__ w_q8,
            const unsigned char* __restrict__ lut8,
            const float* __restrict__ b_int, const float* __restrict__ scale_o,
            unsigned* cnt, float* __restrict__ out) {
    __shared__ char sW[2][12288];       // [192][64] i8, XOR-swizzled
    __shared__ char sX[2][5120];        // [80][64] i8 (hw rows), XOR-swizzled
    __shared__ unsigned char s_lut[2305];
    __shared__ float red[4];
    const int tid = threadIdx.x;
    const int b = blockIdx.z;
    const int hw0 = blockIdx.x * 80;
    const int L = tid & 63;
    const int wv = tid >> 6;
    const int wo = wv * 48;
    const char* pooled_b = (const char*)pooled;

    for (int i = tid; i < 2305; i += 256) s_lut[i] = lut8[i];

    // X staging: 640 items (80 rows x 8 chan-chunks of 8). item -> row=item>>3, ch=item&7.
    // Each item: one uint4 (8 int16) load -> 8 int8 codes -> uint2 LDS write.
    const int row0 = tid >> 3, ch0 = tid & 7;               // item = tid
    const int row1 = 32 + (tid >> 3), ch1 = tid & 7;        // item = 256+tid
    const int row2 = 64 + (tid >> 3), ch2 = tid & 7;        // item = 512+tid (tid<128)
    const bool act2 = tid < 128;

    uint4 xr0, xr1, xr2;

    auto stageW = [&](int kt, int buf) {
#pragma unroll
        for (int j = 0; j < 3; ++j) {
            int ldsoff = (wv * 3 + j) * 1024;
            const char* src = (const char*)w_q8 + kt * 12288 + SWZ(ldsoff + L * 16);
            __builtin_amdgcn_global_load_lds(
                (const __attribute__((address_space(1))) unsigned int*)src,
                (__attribute__((address_space(3))) unsigned int*)(&sW[buf][0] + ldsoff),
                16, 0, 0);
        }
    };
    auto ldx = [&](int kt, int row, int ch) -> uint4 {
        uint4 z; z.x = z.y = z.z = z.w = 0u;
        int hw = hw0 + row;
        if (hw >= HW_) return z;
        // channels 64*kt + ch*8 .. +7 live in slab32 (b*24 + 2*kt + (ch>>2)), chunk ch&3
        size_t slab = (size_t)(b * 24 + 2 * kt + (ch >> 2)) * SLAB_BYT;
        return *(const uint4*)(pooled_b + slab + hw * 64 + (ch & 3) * 16);
    };
    auto loadX = [&](int kt) {
        xr0 = ldx(kt, row0, ch0);
        xr1 = ldx(kt, row1, ch1);
        if (act2) xr2 = ldx(kt, row2, ch2);
    };
    auto pack8 = [&](const uint4& v) -> uint2 {
        unsigned c0 = s_lut[1152 + (short)(v.x)];
        unsigned c1 = s_lut[1152 + (short)(v.x >> 16)];
        unsigned c2 = s_lut[1152 + (short)(v.y)];
        unsigned c3 = s_lut[1152 + (short)(v.y >> 16)];
        unsigned c4 = s_lut[1152 + (short)(v.z)];
        unsigned c5 = s_lut[1152 + (short)(v.z >> 16)];
        unsigned c6 = s_lut[1152 + (short)(v.w)];
        unsigned c7 = s_lut[1152 + (short)(v.w >> 16)];
        uint2 r;
        r.x = c0 | (c1 << 8) | (c2 << 16) | (c3 << 24);
        r.y = c4 | (c5 << 8) | (c6 << 16) | (c7 << 24);
        return r;
    };
    auto writeX = [&](int buf) {
        *(uint2*)(&sX[buf][0] + SWZ(row0 * 64 + ch0 * 8)) = pack8(xr0);
        *(uint2*)(&sX[buf][0] + SWZ(row1 * 64 + ch1 * 8)) = pack8(xr1);
        if (act2) *(uint2*)(&sX[buf][0] + SWZ(row2 * 64 + ch2 * 8)) = pack8(xr2);
    };

    i32x4 acc[3][5] = {};

    stageW(0, 0);
    loadX(0);
    __syncthreads();   // s_lut ready (also drains W(0))
    writeX(0);
    __syncthreads();   // buf0 ready

    for (int kt = 0; kt < 12; ++kt) {
        const int cur = kt & 1, nxt = cur ^ 1;
        if (kt < 11) {
            stageW(kt + 1, nxt);
            loadX(kt + 1);
        }
        i32x4 af[3], bfr[5];
#pragma unroll
        for (int m = 0; m < 3; ++m)
            af[m] = *(const i32x4*)(&sW[cur][0] +
                SWZ((wo + m * 16 + (L & 15)) * 64 + (L >> 4) * 16));
#pragma unroll
        for (int n = 0; n < 5; ++n)
            bfr[n] = *(const i32x4*)(&sX[cur][0] +
                SWZ((n * 16 + (L & 15)) * 64 + (L >> 4) * 16));
#pragma unroll
        for (int m = 0; m < 3; ++m)
#pragma unroll
            for (int n = 0; n < 5; ++n)
                acc[m][n] = __builtin_amdgcn_mfma_i32_16x16x64_i8(
                    af[m], bfr[n], acc[m][n], 0, 0, 0);
        if (kt < 11) writeX(nxt);
        __syncthreads();
    }

    float lmax = 0.f;
#pragma unroll
    for (int m = 0; m < 3; ++m) {
        int ob = wo + m * 16 + (L >> 4) * 4;
        float bi0 = b_int[ob + 0], bi1 = b_int[ob + 1];
        float bi2 = b_int[ob + 2], bi3 = b_int[ob + 3];
        float sc0 = scale_o[ob + 0], sc1 = scale_o[ob + 1];
        float sc2 = scale_o[ob + 2], sc3 = scale_o[ob + 3];
#pragma unroll
        for (int n = 0; n < 5; ++n) {
            int hw = hw0 + n * 16 + (L & 15);
            if (hw < HW_) {
                size_t base = ((size_t)b * O_ + ob) * HW_ + hw;
                float v0 = fmaxf(((float)acc[m][n][0] + bi0) * sc0, 0.f);
                float v1 = fmaxf(((float)acc[m][n][1] + bi1) * sc1, 0.f);
                float v2 = fmaxf(((float)acc[m][n][2] + bi2) * sc2, 0.f);
                float v3 = fmaxf(((float)acc[m][n][3] + bi3) * sc3, 0.f);
                out[base + 0 * HW_] = v0;
                out[base + 1 * HW_] = v1;
                out[base + 2 * HW_] = v2;
                out[base + 3 * HW_] = v3;
                lmax = fmaxf(fmaxf(fmaxf(v0, v1), fmaxf(v2, v3)), lmax);
            }
        }
    }
#pragma unroll
    for (int off = 32; off; off >>= 1) lmax = fmaxf(lmax, __shfl_down(lmax, off));
    if (L == 0) red[wv] = lmax;
    __syncthreads();
    if (tid == 0) {
        float bm = fmaxf(fmaxf(red[0], red[1]), fmaxf(red[2], red[3]));
        atomicMax(cnt + 2, __float_as_uint(bm));
    }
}

__global__ void k_quant_out(float* __restrict__ out, const unsigned* __restrict__ cnt) {
    const float s2 = fmaxf(__uint_as_float(cnt[2]) / QN_, 1e-8f);
    float4* o4 = (float4*)out;
    const int n4 = N_OUT / 4;
    for (int i = blockIdx.x * blockDim.x + threadIdx.x; i < n4;
         i += gridDim.x * blockDim.x) {
        float4 v = o4[i];
        v.x = fminf(fmaxf(rintf(v.x / s2), -128.f), 127.f) * s2;
        v.y = fminf(fmaxf(rintf(v.y / s2), -128.f), 127.f) * s2;
        v.z = fminf(fmaxf(rintf(v.z / s2), -128.f), 127.f) * s2;
        v.w = fminf(fmaxf(rintf(v.w / s2), -128.f), 127.f) * s2;
        o4[i] = v;
    }
    if (blockIdx.x == 0 && threadIdx.x == 0) out[N_OUT] = s2;
}

extern "C" void kernel_launch(void* const* d_in, const int* in_sizes, int n_in,
                              void* d_out, int out_size, void* d_ws, size_t ws_size,
                              hipStream_t stream) {
    const float* x      = (const float*)d_in[0];
    const float* conv_w = (const float*)d_in[1];
    const float* g      = (const float*)d_in[2];
    const float* beta   = (const float*)d_in[3];
    const float* mu     = (const float*)d_in[4];
    const float* var    = (const float*)d_in[5];
    float* out = (float*)d_out;

    char* wsb = (char*)d_ws;
    unsigned* cnt          = (unsigned*)wsb;
    float* b_int           = (float*)(wsb + 1024);
    float* scale_o         = (float*)(wsb + 2048);
    unsigned char* lut8    = (unsigned char*)(wsb + 3072);
    signed char* w_q8      = (signed char*)(wsb + 8192);
    short* pooled          = (short*)(wsb + (1u << 20));

    hipMemsetAsync(cnt, 0, 16, stream);
    k_absmax_x<<<2048, 256, 0, stream>>>((const float4*)x, N_IN / 4, cnt);
    dim3 qgrid(24, 1, B_);
    k_quant_pool<<<qgrid, 512, 0, stream>>>(x, pooled, cnt);
    k_weights<<<O_ + 1, 256, 0, stream>>>(conv_w, g, beta, mu, var, cnt, w_q8,
                                          b_int, scale_o, lut8);
    dim3 ggrid(4, 1, B_);
    k_gemm<<<ggrid, 256, 0, stream>>>(pooled, w_q8, lut8, b_int, scale_o, cnt, out);
    k_quant_out<<<2048, 256, 0, stream>>>(out, cnt);
}

// Round 15
// 129.424 us; speedup vs baseline: 1.9453x; 1.0220x over previous
//
#include <hip/hip_runtime.h>
#include <math.h>

#define B_    128
#define C_    768
#define O_    192
#define HW_   289
#define N_IN  (128*768*289)
#define N_OUT (128*192*289)
#define QN_   127.0f

// quant_pool: block = (b, kt32) slab of 32 planes; padded LDS [32][19][20] f32
#define SLAB_E   (32*289)           // 9248 elements per slab
#define SLAB_SH  9248               // shorts per pooled slab
#define SLAB_BYT 18496              // bytes per pooled slab
#define QP_LDS   (32*380)           // 12160 f32

typedef __attribute__((ext_vector_type(4))) int i32x4;

// XOR swizzle within a 64B row: flip 16B-chunk bits (4..5) by row bits (6..7). Involution.
#define SWZ(b) ((b) ^ ((((b) >> 6) & 3) << 4))

// ws layout:
//  0     : cnt[0]=absmax(x) bits, cnt[1]=max|pooled| int, cnt[2]=absmax(out) bits
//  4096  : f32 wsf_g[192]
//  5120  : f32 bf_g[192]
//  8192  : i8 w_q8 image, [kt64][o][64c] linear, 12*12288 B
//  1MiB  : i16 pooled[3072 slabs][289][32]

__global__ void k_absmax_x(const float4* __restrict__ x4, int n4, unsigned* cnt) {
    float m = 0.f;
    const int stride = gridDim.x * blockDim.x;
    int i = blockIdx.x * blockDim.x + threadIdx.x;
    for (; i + stride < n4; i += 2 * stride) {
        float4 v = x4[i];
        float4 w = x4[i + stride];
        m = fmaxf(m, fmaxf(fmaxf(fabsf(v.x), fabsf(v.y)),
                           fmaxf(fabsf(v.z), fabsf(v.w))));
        m = fmaxf(m, fmaxf(fmaxf(fabsf(w.x), fabsf(w.y)),
                           fmaxf(fabsf(w.z), fabsf(w.w))));
    }
    if (i < n4) {
        float4 v = x4[i];
        m = fmaxf(m, fmaxf(fmaxf(fabsf(v.x), fabsf(v.y)),
                           fmaxf(fabsf(v.z), fabsf(v.w))));
    }
#pragma unroll
    for (int off = 32; off; off >>= 1) m = fmaxf(m, __shfl_down(m, off));
    __shared__ float sm[4];
    int lane = threadIdx.x & 63, wv = threadIdx.x >> 6;
    if (lane == 0) sm[wv] = m;
    __syncthreads();
    if (threadIdx.x == 0) {
        float bm = fmaxf(fmaxf(sm[0], sm[1]), fmaxf(sm[2], sm[3]));
        atomicMax(cnt + 0, __float_as_uint(bm));
    }
}

// Quantize + 3x3 zero-pad pooling. Block = (kt32, b): 32 planes.
// Border-only LDS zeroing merged with quant scatter: one barrier.
__launch_bounds__(512) __global__
void k_quant_pool(const float* __restrict__ x, short* __restrict__ pooled,
                  unsigned* cnt) {
    __shared__ __align__(16) float fq[QP_LDS + 8];
    __shared__ int smax[8];
    const int tid = threadIdx.x;
    const int kt = blockIdx.x;          // 0..23
    const int b = blockIdx.z;           // 0..127
    const float s0 = fmaxf(__uint_as_float(cnt[0]) / QN_, 1e-8f);

    // zero border slots (91 per plane) + tail pad
    for (int i = tid; i < 32 * 91; i += 512) {
        int p = i / 91, rem = i - p * 91;
        int slot;
        if (rem < 20) slot = rem;                       // row 0
        else if (rem < 40) slot = 360 + (rem - 20);     // row 18
        else {
            int t = rem - 40;
            int rr = t / 3, cc = t - rr * 3;            // rows 1..17, cols {0,18,19}
            slot = (rr + 1) * 20 + (cc == 0 ? 0 : 17 + cc);
        }
        fq[p * 380 + slot] = 0.f;
    }
    if (tid < 8) fq[QP_LDS + tid] = 0.f;

    // quant scatter: interior slots (disjoint from borders)
    const float4* xg4 = (const float4*)(x + ((size_t)b * 768 + kt * 32) * HW_);
    for (int t = tid; t < SLAB_E / 4; t += 512) {
        float4 v = xg4[t];
        float q0 = rintf(v.x / s0);
        float q1 = rintf(v.y / s0);
        float q2 = rintf(v.z / s0);
        float q3 = rintf(v.w / s0);
        int e = 4 * t;
#pragma unroll
        for (int j = 0; j < 4; ++j) {
            float q = (j == 0) ? q0 : (j == 1) ? q1 : (j == 2) ? q2 : q3;
            int ej = e + j;
            int p = (ej * 29027) >> 23;            // ej/289
            int i2 = ej - p * 289;
            int r = (i2 * 3856) >> 16;             // i2/17
            int c = i2 - r * 17;
            fq[p * 380 + (r + 1) * 20 + (c + 1)] = q;
        }
    }
    __syncthreads();

    short* slab = pooled + (size_t)(b * 24 + kt) * SLAB_SH;
    int tmax = 0;
    for (int task = tid; task < 2720; task += 512) {
        int p = task & 31;
        int rt = task >> 5;                 // 0..84
        int r = (rt * 3277) >> 14;          // rt/5
        int t5 = rt - r * 5;
        int c0 = t5 * 4;
        const float* base = fq + p * 380 + r * 20 + c0;
        float4 a0 = *(const float4*)(base);
        float4 a1 = *(const float4*)(base + 4);
        float4 b0 = *(const float4*)(base + 20);
        float4 b1 = *(const float4*)(base + 24);
        float4 d0 = *(const float4*)(base + 40);
        float4 d1 = *(const float4*)(base + 44);
        float s0c = a0.x + b0.x + d0.x;
        float s1c = a0.y + b0.y + d0.y;
        float s2c = a0.z + b0.z + d0.z;
        float s3c = a0.w + b0.w + d0.w;
        float s4c = a1.x + b1.x + d1.x;
        float s5c = a1.y + b1.y + d1.y;
        int o0 = (int)(s0c + s1c + s2c);
        int o1 = (int)(s1c + s2c + s3c);
        int o2 = (int)(s2c + s3c + s4c);
        int o3 = (int)(s3c + s4c + s5c);
        int i0 = r * 17 + c0;
        slab[(i0 + 0) * 32 + p] = (short)o0;
        int a = o0 < 0 ? -o0 : o0; tmax = a > tmax ? a : tmax;
        if (c0 + 1 < 17) {
            slab[(i0 + 1) * 32 + p] = (short)o1;
            a = o1 < 0 ? -o1 : o1; tmax = a > tmax ? a : tmax;
            slab[(i0 + 2) * 32 + p] = (short)o2;
            a = o2 < 0 ? -o2 : o2; tmax = a > tmax ? a : tmax;
            slab[(i0 + 3) * 32 + p] = (short)o3;
            a = o3 < 0 ? -o3 : o3; tmax = a > tmax ? a : tmax;
        }
    }

#pragma unroll
    for (int off = 32; off; off >>= 1) {
        int o = __shfl_down(tmax, off);
        tmax = o > tmax ? o : tmax;
    }
    if ((tid & 63) == 0) smax[tid >> 6] = tmax;
    __syncthreads();
    if (tid == 0) {
        int bm = smax[0];
#pragma unroll
        for (int i = 1; i < 8; ++i) bm = smax[i] > bm ? smax[i] : bm;
        atomicMax((int*)(cnt + 1), bm);
    }
}

// cnt-independent weight prep: per-channel wsf, int8 image, bf. Runs before absmax.
__global__ void k_weights_pre(const float* __restrict__ conv_w,
                              const float* __restrict__ g,
                              const float* __restrict__ beta,
                              const float* __restrict__ mu,
                              const float* __restrict__ var,
                              signed char* __restrict__ w_q8,
                              float* __restrict__ wsf_g, float* __restrict__ bf_g) {
    const int o = blockIdx.x;
    const float stdv = sqrtf(var[o] + 1e-5f);
    const float r = g[o] / stdv;
    const float* wo = conv_w + o * C_;
    float m = 0.f;
    for (int c = threadIdx.x; c < C_; c += 256) m = fmaxf(m, fabsf(wo[c] * r));
#pragma unroll
    for (int off = 32; off; off >>= 1) m = fmaxf(m, __shfl_down(m, off));
    __shared__ float sm[4];
    __shared__ float swsf;
    int lane = threadIdx.x & 63, wv = threadIdx.x >> 6;
    if (lane == 0) sm[wv] = m;
    __syncthreads();
    if (threadIdx.x == 0) {
        float bm = fmaxf(fmaxf(sm[0], sm[1]), fmaxf(sm[2], sm[3]));
        swsf = fmaxf(bm / QN_, 1e-8f);
    }
    __syncthreads();
    const float wsf = swsf;
    for (int c = threadIdx.x; c < C_; c += 256) {
        float wi = rintf(wo[c] * r / wsf);
        wi = fminf(fmaxf(wi, -128.f), 127.f);
        w_q8[(c >> 6) * 12288 + o * 64 + (c & 63)] = (signed char)(int)wi;
    }
    if (threadIdx.x == 0) {
        wsf_g[o] = wsf;
        bf_g[o] = beta[o] - g[o] * mu[o] / stdv;
    }
}

// int8 MFMA GEMM with in-block LUT + channel-scalar prologue.
__launch_bounds__(256) __global__
void k_gemm(const short* __restrict__ pooled,
            const signed char* __restrict__ w_q8,
            const float* __restrict__ wsf_g, const float* __restrict__ bf_g,
            unsigned* cnt, float* __restrict__ out) {
    __shared__ char sW[2][12288];       // [192][64] i8, XOR-swizzled
    __shared__ char sX[2][5120];        // [80][64] i8 (hw rows), XOR-swizzled
    __shared__ unsigned char s_lut[2305];
    __shared__ float s_bint[192];
    __shared__ float s_scale[192];
    __shared__ float red[4];
    const int tid = threadIdx.x;
    const int b = blockIdx.z;
    const int hw0 = blockIdx.x * 80;
    const int L = tid & 63;
    const int wv = tid >> 6;
    const int wo = wv * 48;
    const char* pooled_b = (const char*)pooled;

    // prologue: LUT + per-channel scalars (same fp32 formulas as before -> bit-identical)
    {
        const float s0 = fmaxf(__uint_as_float(cnt[0]) / QN_, 1e-8f);
        const float maxx2 = ((float)((const int*)cnt)[1] / 9.0f) * s0;
        const float s1 = fmaxf(maxx2 / QN_, 1e-8f);
        for (int i = tid; i < 2305; i += 256) {
            float p = (float)(i - 1152);
            float t = (p / 9.0f) * s0;
            float v = rintf(t / s1);
            v = fminf(fmaxf(v, -128.f), 127.f);
            s_lut[i] = (unsigned char)(signed char)(int)v;
        }
        if (tid < 192) {
            float wsf = wsf_g[tid];
            s_bint[tid] = rintf(bf_g[tid] / (wsf * s1));
            s_scale[tid] = wsf * s1;
        }
    }

    const int row0 = tid >> 3, ch0 = tid & 7;               // item = tid
    const int row1 = 32 + (tid >> 3), ch1 = tid & 7;        // item = 256+tid
    const int row2 = 64 + (tid >> 3), ch2 = tid & 7;        // item = 512+tid (tid<128)
    const bool act2 = tid < 128;

    uint4 xr0, xr1, xr2;

    auto stageW = [&](int kt, int buf) {
#pragma unroll
        for (int j = 0; j < 3; ++j) {
            int ldsoff = (wv * 3 + j) * 1024;
            const char* src = (const char*)w_q8 + kt * 12288 + SWZ(ldsoff + L * 16);
            __builtin_amdgcn_global_load_lds(
                (const __attribute__((address_space(1))) unsigned int*)src,
                (__attribute__((address_space(3))) unsigned int*)(&sW[buf][0] + ldsoff),
                16, 0, 0);
        }
    };
    auto ldx = [&](int kt, int row, int ch) -> uint4 {
        uint4 z; z.x = z.y = z.z = z.w = 0u;
        int hw = hw0 + row;
        if (hw >= HW_) return z;
        size_t slab = (size_t)(b * 24 + 2 * kt + (ch >> 2)) * SLAB_BYT;
        return *(const uint4*)(pooled_b + slab + hw * 64 + (ch & 3) * 16);
    };
    auto loadX = [&](int kt) {
        xr0 = ldx(kt, row0, ch0);
        xr1 = ldx(kt, row1, ch1);
        if (act2) xr2 = ldx(kt, row2, ch2);
    };
    auto pack8 = [&](const uint4& v) -> uint2 {
        unsigned c0 = s_lut[1152 + (short)(v.x)];
        unsigned c1 = s_lut[1152 + (short)(v.x >> 16)];
        unsigned c2 = s_lut[1152 + (short)(v.y)];
        unsigned c3 = s_lut[1152 + (short)(v.y >> 16)];
        unsigned c4 = s_lut[1152 + (short)(v.z)];
        unsigned c5 = s_lut[1152 + (short)(v.z >> 16)];
        unsigned c6 = s_lut[1152 + (short)(v.w)];
        unsigned c7 = s_lut[1152 + (short)(v.w >> 16)];
        uint2 r;
        r.x = c0 | (c1 << 8) | (c2 << 16) | (c3 << 24);
        r.y = c4 | (c5 << 8) | (c6 << 16) | (c7 << 24);
        return r;
    };
    auto writeX = [&](int buf) {
        *(uint2*)(&sX[buf][0] + SWZ(row0 * 64 + ch0 * 8)) = pack8(xr0);
        *(uint2*)(&sX[buf][0] + SWZ(row1 * 64 + ch1 * 8)) = pack8(xr1);
        if (act2) *(uint2*)(&sX[buf][0] + SWZ(row2 * 64 + ch2 * 8)) = pack8(xr2);
    };

    i32x4 acc[3][5] = {};

    stageW(0, 0);
    loadX(0);
    __syncthreads();   // s_lut/s_bint ready (also drains W(0))
    writeX(0);
    __syncthreads();   // buf0 ready

    for (int kt = 0; kt < 12; ++kt) {
        const int cur = kt & 1, nxt = cur ^ 1;
        if (kt < 11) {
            stageW(kt + 1, nxt);
            loadX(kt + 1);
        }
        i32x4 af[3], bfr[5];
#pragma unroll
        for (int m = 0; m < 3; ++m)
            af[m] = *(const i32x4*)(&sW[cur][0] +
                SWZ((wo + m * 16 + (L & 15)) * 64 + (L >> 4) * 16));
#pragma unroll
        for (int n = 0; n < 5; ++n)
            bfr[n] = *(const i32x4*)(&sX[cur][0] +
                SWZ((n * 16 + (L & 15)) * 64 + (L >> 4) * 16));
#pragma unroll
        for (int m = 0; m < 3; ++m)
#pragma unroll
            for (int n = 0; n < 5; ++n)
                acc[m][n] = __builtin_amdgcn_mfma_i32_16x16x64_i8(
                    af[m], bfr[n], acc[m][n], 0, 0, 0);
        if (kt < 11) writeX(nxt);
        __syncthreads();
    }

    float lmax = 0.f;
#pragma unroll
    for (int m = 0; m < 3; ++m) {
        int ob = wo + m * 16 + (L >> 4) * 4;
        float bi0 = s_bint[ob + 0], bi1 = s_bint[ob + 1];
        float bi2 = s_bint[ob + 2], bi3 = s_bint[ob + 3];
        float sc0 = s_scale[ob + 0], sc1 = s_scale[ob + 1];
        float sc2 = s_scale[ob + 2], sc3 = s_scale[ob + 3];
#pragma unroll
        for (int n = 0; n < 5; ++n) {
            int hw = hw0 + n * 16 + (L & 15);
            if (hw < HW_) {
                size_t base = ((size_t)b * O_ + ob) * HW_ + hw;
                float v0 = fmaxf(((float)acc[m][n][0] + bi0) * sc0, 0.f);
                float v1 = fmaxf(((float)acc[m][n][1] + bi1) * sc1, 0.f);
                float v2 = fmaxf(((float)acc[m][n][2] + bi2) * sc2, 0.f);
                float v3 = fmaxf(((float)acc[m][n][3] + bi3) * sc3, 0.f);
                out[base + 0 * HW_] = v0;
                out[base + 1 * HW_] = v1;
                out[base + 2 * HW_] = v2;
                out[base + 3 * HW_] = v3;
                lmax = fmaxf(fmaxf(fmaxf(v0, v1), fmaxf(v2, v3)), lmax);
            }
        }
    }
#pragma unroll
    for (int off = 32; off; off >>= 1) lmax = fmaxf(lmax, __shfl_down(lmax, off));
    if (L == 0) red[wv] = lmax;
    __syncthreads();
    if (tid == 0) {
        float bm = fmaxf(fmaxf(red[0], red[1]), fmaxf(red[2], red[3]));
        atomicMax(cnt + 2, __float_as_uint(bm));
    }
}

__global__ void k_quant_out(float* __restrict__ out, const unsigned* __restrict__ cnt) {
    const float s2 = fmaxf(__uint_as_float(cnt[2]) / QN_, 1e-8f);
    float4* o4 = (float4*)out;
    const int n4 = N_OUT / 4;
    for (int i = blockIdx.x * blockDim.x + threadIdx.x; i < n4;
         i += gridDim.x * blockDim.x) {
        float4 v = o4[i];
        v.x = fminf(fmaxf(rintf(v.x / s2), -128.f), 127.f) * s2;
        v.y = fminf(fmaxf(rintf(v.y / s2), -128.f), 127.f) * s2;
        v.z = fminf(fmaxf(rintf(v.z / s2), -128.f), 127.f) * s2;
        v.w = fminf(fmaxf(rintf(v.w / s2), -128.f), 127.f) * s2;
        o4[i] = v;
    }
    if (blockIdx.x == 0 && threadIdx.x == 0) out[N_OUT] = s2;
}

extern "C" void kernel_launch(void* const* d_in, const int* in_sizes, int n_in,
                              void* d_out, int out_size, void* d_ws, size_t ws_size,
                              hipStream_t stream) {
    const float* x      = (const float*)d_in[0];
    const float* conv_w = (const float*)d_in[1];
    const float* g      = (const float*)d_in[2];
    const float* beta   = (const float*)d_in[3];
    const float* mu     = (const float*)d_in[4];
    const float* var    = (const float*)d_in[5];
    float* out = (float*)d_out;

    char* wsb = (char*)d_ws;
    unsigned* cnt          = (unsigned*)wsb;
    float* wsf_g           = (float*)(wsb + 4096);
    float* bf_g            = (float*)(wsb + 5120);
    signed char* w_q8      = (signed char*)(wsb + 8192);
    short* pooled          = (short*)(wsb + (1u << 20));

    hipMemsetAsync(cnt, 0, 16, stream);
    k_weights_pre<<<O_, 256, 0, stream>>>(conv_w, g, beta, mu, var, w_q8, wsf_g,
                                          bf_g);
    k_absmax_x<<<2048, 256, 0, stream>>>((const float4*)x, N_IN / 4, cnt);
    dim3 qgrid(24, 1, B_);
    k_quant_pool<<<qgrid, 512, 0, stream>>>(x, pooled, cnt);
    dim3 ggrid(4, 1, B_);
    k_gemm<<<ggrid, 256, 0, stream>>>(pooled, w_q8, wsf_g, bf_g, cnt, out);
    k_quant_out<<<2048, 256, 0, stream>>>(out, cnt);
}